// Round 6
// baseline (56.795 us; speedup 1.0000x reference)
//
#include <hip/hip_runtime.h>
#include <hip/hip_bf16.h>

// B=2, L=512, H_IN=768, E=256, N=12. M = B*L = 1024.
// out[b,i,n,j] = sum_e key[b,i,e,n]*t[b,j,e]
//             + sum_e relu(su[b,i,e]+tv[b,j,e]+f2b[e])*f3W[n,e] + f3b[n]
// All intermediates fp16. key/tv consumed register-direct (single-consumer).

typedef unsigned short u16;
typedef __attribute__((ext_vector_type(8))) short    s16x8;
typedef __attribute__((ext_vector_type(8))) _Float16 f16x8;
typedef __attribute__((ext_vector_type(4))) float    f32x4;

__device__ inline u16 f2h(float f) { return __builtin_bit_cast(u16, (_Float16)f); }

__device__ inline s16x8 cvt2(float4 a, float4 b) {
    f16x8 h;
    h[0] = (_Float16)a.x; h[1] = (_Float16)a.y; h[2] = (_Float16)a.z; h[3] = (_Float16)a.w;
    h[4] = (_Float16)b.x; h[5] = (_Float16)b.y; h[6] = (_Float16)b.z; h[7] = (_Float16)b.w;
    return __builtin_bit_cast(s16x8, h);
}

__device__ inline f32x4 mfma_f16(s16x8 a, s16x8 b, f32x4 c) {
    return __builtin_amdgcn_mfma_f32_16x16x32_f16(
        __builtin_bit_cast(f16x8, a), __builtin_bit_cast(f16x8, b), c, 0, 0, 0);
}
__device__ inline f32x4 mfma_f16v(f16x8 a, s16x8 b, f32x4 c) {
    return __builtin_amdgcn_mfma_f32_16x16x32_f16(a, __builtin_bit_cast(f16x8, b), c, 0, 0, 0);
}

// ---------------- weights conversion / permutation (float4-wide) ----------------
// blkw [3584][256]: rows 0..3071 perm(blW), 3072..3327 Wu, 3328..3583 Wv. f3wb [16][256].
__global__ __launch_bounds__(256)
void conv_kernel(const float* __restrict__ f2W, const float* __restrict__ blW,
                 const float* __restrict__ f3W,
                 u16* __restrict__ blkw, u16* __restrict__ f3wb)
{
    int idx = blockIdx.x * 256 + threadIdx.x;
    if (idx >= 230400) return;
    float4 v;
    u16* dst;
    if (idx < 229376) {
        int i4 = idx * 4;
        int r = i4 >> 8, k = i4 & 255;
        const float* src;
        if (r < 3072)      { int n = r >> 8, e = r & 255; src = &blW[(e * 12 + n) * 256 + k]; }
        else if (r < 3328) { src = &f2W[(r - 3072) * 512 + k]; }
        else               { src = &f2W[(r - 3328) * 512 + 256 + k]; }
        v = *(const float4*)src;
        dst = &blkw[i4];
    } else {
        int i4 = (idx - 229376) * 4;
        int row = i4 >> 8, e = i4 & 255;
        if (row < 12) v = *(const float4*)&f3W[row * 256 + e];
        else          v = make_float4(0.f, 0.f, 0.f, 0.f);
        dst = &f3wb[i4];
    }
    ushort4 o;
    o.x = f2h(v.x); o.y = f2h(v.y); o.z = f2h(v.z); o.w = f2h(v.w);
    *(ushort4*)dst = o;
}

// ---------------- s|t GEMM from f32 inputs: STb = relu(x @ [sW;tW]^T + [sb;tb]) ----------------
// 64x64 tile, BK=64, K=768, 256 threads, f32 loads converted to f16 during staging.
__global__ __launch_bounds__(256, 2)
void gemm_st(const float* __restrict__ x, const float* __restrict__ sW,
             const float* __restrict__ tW, const float* __restrict__ sb,
             const float* __restrict__ tb, u16* __restrict__ STb)
{
    __shared__ u16 As[64 * 72];
    __shared__ u16 Bs[64 * 72];
    const int tid = threadIdx.x;
    const int m0 = blockIdx.y * 64, n0 = blockIdx.x * 64;
    const int w = tid >> 6, l = tid & 63;
    const int wr = (w >> 1) * 32, wc = (w & 1) * 32;
    const int lr = l & 15, lg = l >> 4;
    const int srow = tid >> 2, kq = tid & 3;

    const float* ap = &x[(size_t)(m0 + srow) * 768 + kq * 16];
    int brow = n0 + srow;
    const float* bp = (brow < 256) ? &sW[(size_t)brow * 768 + kq * 16]
                                   : &tW[(size_t)(brow - 256) * 768 + kq * 16];
    float4 ra0 = *(const float4*)(ap + 0),  ra1 = *(const float4*)(ap + 4);
    float4 ra2 = *(const float4*)(ap + 8),  ra3 = *(const float4*)(ap + 12);
    float4 rb0 = *(const float4*)(bp + 0),  rb1 = *(const float4*)(bp + 4);
    float4 rb2 = *(const float4*)(bp + 8),  rb3 = *(const float4*)(bp + 12);

    f32x4 acc[2][2] = {};
    for (int k0 = 0; k0 < 768; k0 += 64) {
        __syncthreads();
        *(s16x8*)&As[srow * 72 + kq * 16]     = cvt2(ra0, ra1);
        *(s16x8*)&As[srow * 72 + kq * 16 + 8] = cvt2(ra2, ra3);
        *(s16x8*)&Bs[srow * 72 + kq * 16]     = cvt2(rb0, rb1);
        *(s16x8*)&Bs[srow * 72 + kq * 16 + 8] = cvt2(rb2, rb3);
        __syncthreads();
        if (k0 + 64 < 768) {
            ra0 = *(const float4*)(ap + k0 + 64 + 0);  ra1 = *(const float4*)(ap + k0 + 64 + 4);
            ra2 = *(const float4*)(ap + k0 + 64 + 8);  ra3 = *(const float4*)(ap + k0 + 64 + 12);
            rb0 = *(const float4*)(bp + k0 + 64 + 0);  rb1 = *(const float4*)(bp + k0 + 64 + 4);
            rb2 = *(const float4*)(bp + k0 + 64 + 8);  rb3 = *(const float4*)(bp + k0 + 64 + 12);
        }
#pragma unroll
        for (int kk = 0; kk < 64; kk += 32) {
            s16x8 af[2], bf[2];
            af[0] = *(const s16x8*)&As[(wr      + lr) * 72 + kk + lg * 8];
            af[1] = *(const s16x8*)&As[(wr + 16 + lr) * 72 + kk + lg * 8];
            bf[0] = *(const s16x8*)&Bs[(wc      + lr) * 72 + kk + lg * 8];
            bf[1] = *(const s16x8*)&Bs[(wc + 16 + lr) * 72 + kk + lg * 8];
#pragma unroll
            for (int fi = 0; fi < 2; ++fi)
#pragma unroll
                for (int fj = 0; fj < 2; ++fj)
                    acc[fi][fj] = mfma_f16(af[fi], bf[fj], acc[fi][fj]);
        }
    }
#pragma unroll
    for (int fi = 0; fi < 2; ++fi) {
#pragma unroll
        for (int fj = 0; fj < 2; ++fj) {
#pragma unroll
            for (int r = 0; r < 4; ++r) {
                int grow = m0 + wr + fi * 16 + lg * 4 + r;
                int gcol = n0 + wc + fj * 16 + lr;
                float bias = (gcol < 256) ? sb[gcol] : tb[gcol - 256];
                float v = fmaxf(acc[fi][fj][r] + bias, 0.f);
                STb[(size_t)grow * 512 + gcol] = f2h(v);
            }
        }
    }
}

// ---------------- key+su+tv GEMM: one launch, N=3584, K=256 ----------------
// cols 0..3071 -> KEYP[n][1024][256]; 3072..3327 -> SU; 3328..3583 -> TV (+f2b).
// A = s (STb cols 0..255) for cols<3328, t (cols 256..511) for tv range.
__global__ __launch_bounds__(256, 2)
void gemm_kst(const u16* __restrict__ STb, const u16* __restrict__ BLKW,
              const float* __restrict__ f2b,
              u16* __restrict__ KEYP, u16* __restrict__ SUp, u16* __restrict__ TVp)
{
    __shared__ u16 As[64 * 72];
    __shared__ u16 Bs[64 * 72];
    const int tid = threadIdx.x;
    const int m0 = blockIdx.y * 64, n0 = blockIdx.x * 64;
    const int w = tid >> 6, l = tid & 63;
    const int wr = (w >> 1) * 32, wc = (w & 1) * 32;
    const int lr = l & 15, lg = l >> 4;
    const int srow = tid >> 2, kq = tid & 3;

    const u16* A = STb + (n0 >= 3328 ? 256 : 0);
    const u16* ap = &A[(size_t)(m0 + srow) * 512];
    const u16* bp = &BLKW[(size_t)(n0 + srow) * 256];
    s16x8 ra0 = *(const s16x8*)&ap[kq * 8];
    s16x8 ra1 = *(const s16x8*)&ap[(kq + 4) * 8];
    s16x8 rb0 = *(const s16x8*)&bp[kq * 8];
    s16x8 rb1 = *(const s16x8*)&bp[(kq + 4) * 8];

    f32x4 acc[2][2] = {};
    for (int k0 = 0; k0 < 256; k0 += 64) {
        __syncthreads();
        *(s16x8*)&As[srow * 72 + kq * 8]       = ra0;
        *(s16x8*)&As[srow * 72 + (kq + 4) * 8] = ra1;
        *(s16x8*)&Bs[srow * 72 + kq * 8]       = rb0;
        *(s16x8*)&Bs[srow * 72 + (kq + 4) * 8] = rb1;
        __syncthreads();
        if (k0 + 64 < 256) {
            ra0 = *(const s16x8*)&ap[k0 + 64 + kq * 8];
            ra1 = *(const s16x8*)&ap[k0 + 64 + (kq + 4) * 8];
            rb0 = *(const s16x8*)&bp[k0 + 64 + kq * 8];
            rb1 = *(const s16x8*)&bp[k0 + 64 + (kq + 4) * 8];
        }
#pragma unroll
        for (int kk = 0; kk < 64; kk += 32) {
            s16x8 af[2], bf[2];
            af[0] = *(const s16x8*)&As[(wr      + lr) * 72 + kk + lg * 8];
            af[1] = *(const s16x8*)&As[(wr + 16 + lr) * 72 + kk + lg * 8];
            bf[0] = *(const s16x8*)&Bs[(wc      + lr) * 72 + kk + lg * 8];
            bf[1] = *(const s16x8*)&Bs[(wc + 16 + lr) * 72 + kk + lg * 8];
#pragma unroll
            for (int fi = 0; fi < 2; ++fi)
#pragma unroll
                for (int fj = 0; fj < 2; ++fj)
                    acc[fi][fj] = mfma_f16(af[fi], bf[fj], acc[fi][fj]);
        }
    }
#pragma unroll
    for (int fi = 0; fi < 2; ++fi) {
#pragma unroll
        for (int fj = 0; fj < 2; ++fj) {
#pragma unroll
            for (int r = 0; r < 4; ++r) {
                int grow = m0 + wr + fi * 16 + lg * 4 + r;
                int gcol = n0 + wc + fj * 16 + lr;
                float v = acc[fi][fj][r];
                if (gcol < 3072) {
                    int n = gcol >> 8, e = gcol & 255;
                    KEYP[(size_t)n * 262144 + (size_t)grow * 256 + e] = f2h(v);
                } else if (gcol < 3328) {
                    SUp[(size_t)grow * 256 + (gcol - 3072)] = f2h(v);
                } else {
                    TVp[(size_t)grow * 256 + (gcol - 3328)] = f2h(v + f2b[gcol - 3328]);
                }
            }
        }
    }
}

// ---------------- fused output kernel ----------------
// grid (16 j, 32 i, 2 b): block = 16i x 32j, 256 thr = 4 waves.
// LDS holds only shared tiles (t, su, f3); key/tv fragments are register-direct
// (single consumer) with 1-iter prefetch. Merge buffer overlays LDS at the end.
__global__ __launch_bounds__(256, 3)
void fused_out(const u16* __restrict__ KEYP, const u16* __restrict__ STb,
               const u16* __restrict__ SUp, const u16* __restrict__ TVp,
               const u16* __restrict__ F3WH, const float* __restrict__ f3b,
               float* __restrict__ out)
{
    __shared__ __align__(16) char smem[27904];
    u16* lds = (u16*)smem;
    const int TC = 0, SUC = 1280, F3C = 1920;   // u16 offsets; ends at 6144 u16

    const int tid = threadIdx.x;
    const int w = tid >> 6, l = tid & 63;
    const int b  = blockIdx.z;
    const int i0 = blockIdx.y * 16;
    const int j0 = blockIdx.x * 32;
    const int lr = l & 15, lg = l >> 4;

    // staging descriptor (t: 128 granules, su: 64)
    const u16* ssrc = nullptr; int sdst = 0;
    if (tid < 128) {
        int jj = tid >> 2, qq = tid & 3;
        ssrc = STb + (size_t)(b * 512 + j0 + jj) * 512 + 256 + qq * 8;
        sdst = TC + jj * 40 + qq * 8;
    } else if (tid < 192) {
        int q = tid - 128, ii = q >> 2, qq = q & 3;
        ssrc = SUp + (size_t)(b * 512 + i0 + ii) * 256 + qq * 8;
        sdst = SUC + ii * 40 + qq * 8;
    }
    const bool stg = (tid < 192);

    // f3c staged once (first read after first in-loop barrier)
#pragma unroll
    for (int rr = 0; rr < 2; ++rr) {
        int g = tid + 256 * rr;
        int row = g >> 5, qq = g & 31;
        *(s16x8*)&lds[F3C + row * 264 + qq * 8] = *(const s16x8*)&F3WH[row * 256 + qq * 8];
    }

    // register-direct sources
    const u16* kp0 = KEYP + (size_t)(3 * w + 0) * 262144 + (size_t)(b * 512 + i0 + lr) * 256 + lg * 8;
    const u16* kp1 = kp0 + 262144;
    const u16* kp2 = kp1 + 262144;
    const u16* tvp = TVp + (size_t)(b * 512 + j0 + w * 8) * 256 + lg * 8;

    s16x8 st = {};
    if (stg) st = *(const s16x8*)ssrc;
    s16x8 kf0 = *(const s16x8*)kp0;
    s16x8 kf1 = *(const s16x8*)kp1;
    s16x8 kf2 = *(const s16x8*)kp2;
    s16x8 tv[8];
#pragma unroll
    for (int jj = 0; jj < 8; ++jj) tv[jj] = *(const s16x8*)(tvp + jj * 256);

    f32x4 acc1[3][2] = {};
    f32x4 acc2[8]    = {};

    for (int it = 0; it < 8; ++it) {
        const int e0 = it * 32;
        __syncthreads();
        if (stg) *(s16x8*)&lds[sdst] = st;
        __syncthreads();
        if (it < 7 && stg) st = *(const s16x8*)(ssrc + e0 + 32);

        // ---- out1: 6 mfma (key frags in regs, t from LDS) ----
        s16x8 tf0 = *(const s16x8*)&lds[TC + lr * 40 + lg * 8];
        s16x8 tf1 = *(const s16x8*)&lds[TC + (16 + lr) * 40 + lg * 8];
        acc1[0][0] = mfma_f16(kf0, tf0, acc1[0][0]);
        acc1[0][1] = mfma_f16(kf0, tf1, acc1[0][1]);
        acc1[1][0] = mfma_f16(kf1, tf0, acc1[1][0]);
        acc1[1][1] = mfma_f16(kf1, tf1, acc1[1][1]);
        acc1[2][0] = mfma_f16(kf2, tf0, acc1[2][0]);
        acc1[2][1] = mfma_f16(kf2, tf1, acc1[2][1]);

        // ---- out2: packed-f16 h (tv in regs) + 8 mfma ----
        f16x8 sv = __builtin_bit_cast(f16x8, *(const s16x8*)&lds[SUC + lr * 40 + lg * 8]);
        s16x8 f3fr = *(const s16x8*)&lds[F3C + lr * 264 + e0 + lg * 8];
#pragma unroll
        for (int jj = 0; jj < 8; ++jj) {
            f16x8 hv = sv + __builtin_bit_cast(f16x8, tv[jj]);
#pragma unroll
            for (int q = 0; q < 8; ++q)
                hv[q] = hv[q] > (_Float16)0.f ? hv[q] : (_Float16)0.f;
            acc2[jj] = mfma_f16v(hv, f3fr, acc2[jj]);
        }

        if (it < 7) {   // prefetch next-iter key/tv fragments
            int off = e0 + 32;
            kf0 = *(const s16x8*)(kp0 + off);
            kf1 = *(const s16x8*)(kp1 + off);
            kf2 = *(const s16x8*)(kp2 + off);
#pragma unroll
            for (int jj = 0; jj < 8; ++jj) tv[jj] = *(const s16x8*)(tvp + jj * 256 + off);
        }
    }

    // ---- merge out2 D[n=lr][i][j] into out1 layout via LDS (overlay), then store ----
    __syncthreads();
    float* mg = (float*)smem;   // [12] x stride 580 f32; i stride 36
    if (lr < 12) {
#pragma unroll
        for (int r = 0; r < 4; ++r) {
            int i = lg * 4 + r;
            f32x4 v0, v1;
            v0[0] = acc2[0][r]; v0[1] = acc2[1][r]; v0[2] = acc2[2][r]; v0[3] = acc2[3][r];
            v1[0] = acc2[4][r]; v1[1] = acc2[5][r]; v1[2] = acc2[6][r]; v1[3] = acc2[7][r];
            *(f32x4*)&mg[lr * 580 + i * 36 + w * 8]     = v0;
            *(f32x4*)&mg[lr * 580 + i * 36 + w * 8 + 4] = v1;
        }
    }
    __syncthreads();
#pragma unroll
    for (int a = 0; a < 3; ++a) {
        int n = 3 * w + a;
        float fb = f3b[n];
#pragma unroll
        for (int fj = 0; fj < 2; ++fj) {
            int j = fj * 16 + lr;
#pragma unroll
            for (int r = 0; r < 4; ++r) {
                int i = lg * 4 + r;
                float vv = acc1[a][fj][r] + mg[n * 580 + i * 36 + j] + fb;
                out[(((size_t)(b * 512 + i0 + i)) * 12 + n) * 512 + j0 + j] = vv;
            }
        }
    }
}

extern "C" void kernel_launch(void* const* d_in, const int* in_sizes, int n_in,
                              void* d_out, int out_size, void* d_ws, size_t ws_size,
                              hipStream_t stream)
{
    const float* x   = (const float*)d_in[0];
    const float* sW  = (const float*)d_in[1];
    const float* sb  = (const float*)d_in[2];
    const float* tW  = (const float*)d_in[3];
    const float* tb  = (const float*)d_in[4];
    const float* f2W = (const float*)d_in[5];
    const float* f2b = (const float*)d_in[6];
    const float* f3W = (const float*)d_in[7];
    const float* f3b = (const float*)d_in[8];
    const float* blW = (const float*)d_in[9];
    float* out = (float*)d_out;

    char* p = (char*)d_ws;
    u16* STb   = (u16*)p; p += 1048576;   // [1024][512] f16 (s|t)
    u16* blkw  = (u16*)p; p += 1835008;   // [3584][256] f16 (blW perm ; Wu ; Wv)
    u16* KEYP  = (u16*)p; p += 6291456;   // [12][1024][256] f16
    u16* SUp   = (u16*)p; p += 524288;    // [1024][256] f16
    u16* TVp   = (u16*)p; p += 524288;    // [1024][256] f16 (tv + f2b)
    u16* f3wbg = (u16*)p; p += 8192;      // [16][256] f16 (f3W zero-padded)

    conv_kernel<<<900, 256, 0, stream>>>(f2W, blW, f3W, blkw, f3wbg);
    gemm_st <<<dim3(8, 16),  256, 0, stream>>>(x, sW, tW, sb, tb, STb);
    gemm_kst<<<dim3(56, 16), 256, 0, stream>>>(STb, blkw, f2b, KEYP, SUp, TVp);
    fused_out<<<dim3(16, 32, 2), 256, 0, stream>>>(KEYP, STb, SUp, TVp, f3wbg, f3b, out);
}

// Round 7
// 52.076 us; speedup vs baseline: 1.0906x; 1.0906x over previous
//
#include <hip/hip_runtime.h>
#include <hip/hip_bf16.h>

// B=2, L=512, H_IN=768, E=256, N=12. M = B*L = 1024.
// out[b,i,n,j] = sum_e key[b,i,e,n]*t[b,j,e]
//             + sum_e relu(su[b,i,e]+tv[b,j,e]+f2b[e])*f3W[n,e] + f3b[n]
// All intermediates fp16.

typedef unsigned short u16;
typedef __attribute__((ext_vector_type(8))) short    s16x8;
typedef __attribute__((ext_vector_type(8))) _Float16 f16x8;
typedef __attribute__((ext_vector_type(4))) float    f32x4;

__device__ inline u16 f2h(float f) { return __builtin_bit_cast(u16, (_Float16)f); }

__device__ inline s16x8 cvt2(float4 a, float4 b) {
    f16x8 h;
    h[0] = (_Float16)a.x; h[1] = (_Float16)a.y; h[2] = (_Float16)a.z; h[3] = (_Float16)a.w;
    h[4] = (_Float16)b.x; h[5] = (_Float16)b.y; h[6] = (_Float16)b.z; h[7] = (_Float16)b.w;
    return __builtin_bit_cast(s16x8, h);
}

__device__ inline f32x4 mfma_f16(s16x8 a, s16x8 b, f32x4 c) {
    return __builtin_amdgcn_mfma_f32_16x16x32_f16(
        __builtin_bit_cast(f16x8, a), __builtin_bit_cast(f16x8, b), c, 0, 0, 0);
}
__device__ inline f32x4 mfma_f16v(f16x8 a, s16x8 b, f32x4 c) {
    return __builtin_amdgcn_mfma_f32_16x16x32_f16(a, __builtin_bit_cast(f16x8, b), c, 0, 0, 0);
}

// ---------------- weights conversion / permutation (float4-wide) ----------------
// blkw [3584][256]: rows 0..3071 perm(blW), 3072..3327 Wu, 3328..3583 Wv. f3wb [16][256].
__global__ __launch_bounds__(256)
void conv_kernel(const float* __restrict__ f2W, const float* __restrict__ blW,
                 const float* __restrict__ f3W,
                 u16* __restrict__ blkw, u16* __restrict__ f3wb)
{
    int idx = blockIdx.x * 256 + threadIdx.x;
    if (idx >= 230400) return;
    float4 v;
    u16* dst;
    if (idx < 229376) {
        int i4 = idx * 4;
        int r = i4 >> 8, k = i4 & 255;
        const float* src;
        if (r < 3072)      { int n = r >> 8, e = r & 255; src = &blW[(e * 12 + n) * 256 + k]; }
        else if (r < 3328) { src = &f2W[(r - 3072) * 512 + k]; }
        else               { src = &f2W[(r - 3328) * 512 + 256 + k]; }
        v = *(const float4*)src;
        dst = &blkw[i4];
    } else {
        int i4 = (idx - 229376) * 4;
        int row = i4 >> 8, e = i4 & 255;
        if (row < 12) v = *(const float4*)&f3W[row * 256 + e];
        else          v = make_float4(0.f, 0.f, 0.f, 0.f);
        dst = &f3wb[i4];
    }
    ushort4 o;
    o.x = f2h(v.x); o.y = f2h(v.y); o.z = f2h(v.z); o.w = f2h(v.w);
    *(ushort4*)dst = o;
}

// ---------------- s|t GEMM from f32 inputs: STb = relu(x @ [sW;tW]^T + [sb;tb]) ----------------
__global__ __launch_bounds__(256, 2)
void gemm_st(const float* __restrict__ x, const float* __restrict__ sW,
             const float* __restrict__ tW, const float* __restrict__ sb,
             const float* __restrict__ tb, u16* __restrict__ STb)
{
    __shared__ u16 As[64 * 72];
    __shared__ u16 Bs[64 * 72];
    const int tid = threadIdx.x;
    const int m0 = blockIdx.y * 64, n0 = blockIdx.x * 64;
    const int w = tid >> 6, l = tid & 63;
    const int wr = (w >> 1) * 32, wc = (w & 1) * 32;
    const int lr = l & 15, lg = l >> 4;
    const int srow = tid >> 2, kq = tid & 3;

    const float* ap = &x[(size_t)(m0 + srow) * 768 + kq * 16];
    int brow = n0 + srow;
    const float* bp = (brow < 256) ? &sW[(size_t)brow * 768 + kq * 16]
                                   : &tW[(size_t)(brow - 256) * 768 + kq * 16];
    float4 ra0 = *(const float4*)(ap + 0),  ra1 = *(const float4*)(ap + 4);
    float4 ra2 = *(const float4*)(ap + 8),  ra3 = *(const float4*)(ap + 12);
    float4 rb0 = *(const float4*)(bp + 0),  rb1 = *(const float4*)(bp + 4);
    float4 rb2 = *(const float4*)(bp + 8),  rb3 = *(const float4*)(bp + 12);

    f32x4 acc[2][2] = {};
    for (int k0 = 0; k0 < 768; k0 += 64) {
        __syncthreads();
        *(s16x8*)&As[srow * 72 + kq * 16]     = cvt2(ra0, ra1);
        *(s16x8*)&As[srow * 72 + kq * 16 + 8] = cvt2(ra2, ra3);
        *(s16x8*)&Bs[srow * 72 + kq * 16]     = cvt2(rb0, rb1);
        *(s16x8*)&Bs[srow * 72 + kq * 16 + 8] = cvt2(rb2, rb3);
        __syncthreads();
        if (k0 + 64 < 768) {
            ra0 = *(const float4*)(ap + k0 + 64 + 0);  ra1 = *(const float4*)(ap + k0 + 64 + 4);
            ra2 = *(const float4*)(ap + k0 + 64 + 8);  ra3 = *(const float4*)(ap + k0 + 64 + 12);
            rb0 = *(const float4*)(bp + k0 + 64 + 0);  rb1 = *(const float4*)(bp + k0 + 64 + 4);
            rb2 = *(const float4*)(bp + k0 + 64 + 8);  rb3 = *(const float4*)(bp + k0 + 64 + 12);
        }
#pragma unroll
        for (int kk = 0; kk < 64; kk += 32) {
            s16x8 af[2], bf[2];
            af[0] = *(const s16x8*)&As[(wr      + lr) * 72 + kk + lg * 8];
            af[1] = *(const s16x8*)&As[(wr + 16 + lr) * 72 + kk + lg * 8];
            bf[0] = *(const s16x8*)&Bs[(wc      + lr) * 72 + kk + lg * 8];
            bf[1] = *(const s16x8*)&Bs[(wc + 16 + lr) * 72 + kk + lg * 8];
#pragma unroll
            for (int fi = 0; fi < 2; ++fi)
#pragma unroll
                for (int fj = 0; fj < 2; ++fj)
                    acc[fi][fj] = mfma_f16(af[fi], bf[fj], acc[fi][fj]);
        }
    }
#pragma unroll
    for (int fi = 0; fi < 2; ++fi) {
#pragma unroll
        for (int fj = 0; fj < 2; ++fj) {
#pragma unroll
            for (int r = 0; r < 4; ++r) {
                int grow = m0 + wr + fi * 16 + lg * 4 + r;
                int gcol = n0 + wc + fj * 16 + lr;
                float bias = (gcol < 256) ? sb[gcol] : tb[gcol - 256];
                float v = fmaxf(acc[fi][fj][r] + bias, 0.f);
                STb[(size_t)grow * 512 + gcol] = f2h(v);
            }
        }
    }
}

// ---------------- key+su+tv GEMM: one launch, N=3584, K=256 ----------------
__global__ __launch_bounds__(256, 2)
void gemm_kst(const u16* __restrict__ STb, const u16* __restrict__ BLKW,
              const float* __restrict__ f2b,
              u16* __restrict__ KEYP, u16* __restrict__ SUp, u16* __restrict__ TVp)
{
    __shared__ u16 As[64 * 72];
    __shared__ u16 Bs[64 * 72];
    const int tid = threadIdx.x;
    const int m0 = blockIdx.y * 64, n0 = blockIdx.x * 64;
    const int w = tid >> 6, l = tid & 63;
    const int wr = (w >> 1) * 32, wc = (w & 1) * 32;
    const int lr = l & 15, lg = l >> 4;
    const int srow = tid >> 2, kq = tid & 3;

    const u16* A = STb + (n0 >= 3328 ? 256 : 0);
    const u16* ap = &A[(size_t)(m0 + srow) * 512];
    const u16* bp = &BLKW[(size_t)(n0 + srow) * 256];
    s16x8 ra0 = *(const s16x8*)&ap[kq * 8];
    s16x8 ra1 = *(const s16x8*)&ap[(kq + 4) * 8];
    s16x8 rb0 = *(const s16x8*)&bp[kq * 8];
    s16x8 rb1 = *(const s16x8*)&bp[(kq + 4) * 8];

    f32x4 acc[2][2] = {};
    for (int k0 = 0; k0 < 256; k0 += 64) {
        __syncthreads();
        *(s16x8*)&As[srow * 72 + kq * 8]       = ra0;
        *(s16x8*)&As[srow * 72 + (kq + 4) * 8] = ra1;
        *(s16x8*)&Bs[srow * 72 + kq * 8]       = rb0;
        *(s16x8*)&Bs[srow * 72 + (kq + 4) * 8] = rb1;
        __syncthreads();
        if (k0 + 64 < 256) {
            ra0 = *(const s16x8*)&ap[k0 + 64 + kq * 8];
            ra1 = *(const s16x8*)&ap[k0 + 64 + (kq + 4) * 8];
            rb0 = *(const s16x8*)&bp[k0 + 64 + kq * 8];
            rb1 = *(const s16x8*)&bp[k0 + 64 + (kq + 4) * 8];
        }
#pragma unroll
        for (int kk = 0; kk < 64; kk += 32) {
            s16x8 af[2], bf[2];
            af[0] = *(const s16x8*)&As[(wr      + lr) * 72 + kk + lg * 8];
            af[1] = *(const s16x8*)&As[(wr + 16 + lr) * 72 + kk + lg * 8];
            bf[0] = *(const s16x8*)&Bs[(wc      + lr) * 72 + kk + lg * 8];
            bf[1] = *(const s16x8*)&Bs[(wc + 16 + lr) * 72 + kk + lg * 8];
#pragma unroll
            for (int fi = 0; fi < 2; ++fi)
#pragma unroll
                for (int fj = 0; fj < 2; ++fj)
                    acc[fi][fj] = mfma_f16(af[fi], bf[fj], acc[fi][fj]);
        }
    }
#pragma unroll
    for (int fi = 0; fi < 2; ++fi) {
#pragma unroll
        for (int fj = 0; fj < 2; ++fj) {
#pragma unroll
            for (int r = 0; r < 4; ++r) {
                int grow = m0 + wr + fi * 16 + lg * 4 + r;
                int gcol = n0 + wc + fj * 16 + lr;
                float v = acc[fi][fj][r];
                if (gcol < 3072) {
                    int n = gcol >> 8, e = gcol & 255;
                    KEYP[(size_t)n * 262144 + (size_t)grow * 256 + e] = f2h(v);
                } else if (gcol < 3328) {
                    SUp[(size_t)grow * 256 + (gcol - 3072)] = f2h(v);
                } else {
                    TVp[(size_t)grow * 256 + (gcol - 3328)] = f2h(v + f2b[gcol - 3328]);
                }
            }
        }
    }
}

// ---------------- fused output kernel (round-5 structure + XCD swizzle) ----------------
// logical grid 1024: (16 j-tiles, 32 i-tiles, 2 b); block = 16i x 32j, 256 thr = 4 waves.
// XCD-swizzle: consecutive-dispatch blocks round-robin XCDs; remap so each XCD owns a
// contiguous run of i-tiles -> KEYP slab + t/tv stay L2-resident per XCD.
__global__ __launch_bounds__(256, 4)
void fused_out(const u16* __restrict__ KEYP, const u16* __restrict__ STb,
               const u16* __restrict__ SUp, const u16* __restrict__ TVp,
               const u16* __restrict__ F3WH, const float* __restrict__ f3b,
               float* __restrict__ out)
{
    __shared__ __align__(16) char smem[30208];
    u16* lds = (u16*)smem;
    const int KEYC = 0, TC = 7680, SUC = 8960, TVC = 9600, F3C = 10880;

    const int tid = threadIdx.x;
    const int w = tid >> 6, l = tid & 63;

    // XCD-aware bijective remap (nwg=1024, 8 XCDs, 128 per XCD)
    const int lin  = blockIdx.x + (blockIdx.y << 4) + (blockIdx.z << 9);
    const int orig = (lin & 7) * 128 + (lin >> 3);
    const int j0 = (orig & 15) * 32;
    const int i0 = ((orig >> 4) & 31) * 16;
    const int b  = orig >> 9;

    const int lr = l & 15, lg = l >> 4;

    // staging descriptors (1088 granules of 16B; rr=4 only for tid<64)
    const u16* sb_[5]; int do_[5];
#pragma unroll
    for (int rr = 0; rr < 5; ++rr) {
        int g = tid + 256 * rr;
        const u16* s = nullptr; int d = 0;
        if (g < 768) {
            int n = g >> 6, ii = (g >> 2) & 15, qq = g & 3;
            s = KEYP + (size_t)n * 262144 + (size_t)(b * 512 + i0 + ii) * 256 + qq * 8;
            d = KEYC + (n * 16 + ii) * 40 + qq * 8;
        } else if (g < 896) {
            int q = g - 768, jj = q >> 2, qq = q & 3;
            s = STb + (size_t)(b * 512 + j0 + jj) * 512 + 256 + qq * 8;
            d = TC + jj * 40 + qq * 8;
        } else if (g < 960) {
            int q = g - 896, ii = q >> 2, qq = q & 3;
            s = SUp + (size_t)(b * 512 + i0 + ii) * 256 + qq * 8;
            d = SUC + ii * 40 + qq * 8;
        } else {
            int q = g - 960, jj = q >> 2, qq = q & 3;
            s = TVp + (size_t)(b * 512 + j0 + jj) * 256 + qq * 8;
            d = TVC + jj * 40 + qq * 8;
        }
        sb_[rr] = s; do_[rr] = d;
    }
    const bool v4 = (tid < 64);

    // f3c staged once
#pragma unroll
    for (int rr = 0; rr < 2; ++rr) {
        int g = tid + 256 * rr;
        int row = g >> 5, qq = g & 31;
        *(s16x8*)&lds[F3C + row * 264 + qq * 8] = *(const s16x8*)&F3WH[row * 256 + qq * 8];
    }

    s16x8 st0, st1, st2, st3, st4 = {};
    f32x4 acc1[3][2] = {};
    f32x4 acc2[8]    = {};

    st0 = *(const s16x8*)(sb_[0]);
    st1 = *(const s16x8*)(sb_[1]);
    st2 = *(const s16x8*)(sb_[2]);
    st3 = *(const s16x8*)(sb_[3]);
    if (v4) st4 = *(const s16x8*)(sb_[4]);

    for (int it = 0; it < 8; ++it) {
        const int e0 = it * 32;
        __syncthreads();
        *(s16x8*)&lds[do_[0]] = st0;
        *(s16x8*)&lds[do_[1]] = st1;
        *(s16x8*)&lds[do_[2]] = st2;
        *(s16x8*)&lds[do_[3]] = st3;
        if (v4) *(s16x8*)&lds[do_[4]] = st4;
        __syncthreads();
        if (it < 7) {   // issue next tile; latency hides under compute below
            st0 = *(const s16x8*)(sb_[0] + e0 + 32);
            st1 = *(const s16x8*)(sb_[1] + e0 + 32);
            st2 = *(const s16x8*)(sb_[2] + e0 + 32);
            st3 = *(const s16x8*)(sb_[3] + e0 + 32);
            if (v4) st4 = *(const s16x8*)(sb_[4] + e0 + 32);
        }
        // ---- out1: 6 mfma ----
        s16x8 tf0 = *(const s16x8*)&lds[TC + lr * 40 + lg * 8];
        s16x8 tf1 = *(const s16x8*)&lds[TC + (16 + lr) * 40 + lg * 8];
#pragma unroll
        for (int a = 0; a < 3; ++a) {
            int n = 3 * w + a;
            s16x8 kf = *(const s16x8*)&lds[KEYC + (n * 16 + lr) * 40 + lg * 8];
            acc1[a][0] = mfma_f16(kf, tf0, acc1[a][0]);
            acc1[a][1] = mfma_f16(kf, tf1, acc1[a][1]);
        }
        // ---- out2: packed-f16 h + 8 mfma ----
        f16x8 sv = __builtin_bit_cast(f16x8, *(const s16x8*)&lds[SUC + lr * 40 + lg * 8]);
        s16x8 f3fr = *(const s16x8*)&lds[F3C + lr * 264 + e0 + lg * 8];
#pragma unroll
        for (int jj = 0; jj < 8; ++jj) {
            int j = w * 8 + jj;
            f16x8 tv8 = __builtin_bit_cast(f16x8, *(const s16x8*)&lds[TVC + j * 40 + lg * 8]);
            f16x8 hv = sv + tv8;
#pragma unroll
            for (int q = 0; q < 8; ++q)
                hv[q] = hv[q] > (_Float16)0.f ? hv[q] : (_Float16)0.f;
            acc2[jj] = mfma_f16v(hv, f3fr, acc2[jj]);
        }
    }

    // ---- merge out2 D[n=lr][i][j] into out1 layout via LDS (overlay), then store ----
    __syncthreads();
    float* mg = (float*)smem;   // [12] x stride 580 f32; i stride 36
    if (lr < 12) {
#pragma unroll
        for (int r = 0; r < 4; ++r) {
            int i = lg * 4 + r;
            f32x4 v0, v1;
            v0[0] = acc2[0][r]; v0[1] = acc2[1][r]; v0[2] = acc2[2][r]; v0[3] = acc2[3][r];
            v1[0] = acc2[4][r]; v1[1] = acc2[5][r]; v1[2] = acc2[6][r]; v1[3] = acc2[7][r];
            *(f32x4*)&mg[lr * 580 + i * 36 + w * 8]     = v0;
            *(f32x4*)&mg[lr * 580 + i * 36 + w * 8 + 4] = v1;
        }
    }
    __syncthreads();
#pragma unroll
    for (int a = 0; a < 3; ++a) {
        int n = 3 * w + a;
        float fb = f3b[n];
#pragma unroll
        for (int fj = 0; fj < 2; ++fj) {
            int j = fj * 16 + lr;
#pragma unroll
            for (int r = 0; r < 4; ++r) {
                int i = lg * 4 + r;
                float vv = acc1[a][fj][r] + mg[n * 580 + i * 36 + j] + fb;
                out[(((size_t)(b * 512 + i0 + i)) * 12 + n) * 512 + j0 + j] = vv;
            }
        }
    }
}

extern "C" void kernel_launch(void* const* d_in, const int* in_sizes, int n_in,
                              void* d_out, int out_size, void* d_ws, size_t ws_size,
                              hipStream_t stream)
{
    const float* x   = (const float*)d_in[0];
    const float* sW  = (const float*)d_in[1];
    const float* sb  = (const float*)d_in[2];
    const float* tW  = (const float*)d_in[3];
    const float* tb  = (const float*)d_in[4];
    const float* f2W = (const float*)d_in[5];
    const float* f2b = (const float*)d_in[6];
    const float* f3W = (const float*)d_in[7];
    const float* f3b = (const float*)d_in[8];
    const float* blW = (const float*)d_in[9];
    float* out = (float*)d_out;

    char* p = (char*)d_ws;
    u16* STb   = (u16*)p; p += 1048576;   // [1024][512] f16 (s|t)
    u16* blkw  = (u16*)p; p += 1835008;   // [3584][256] f16 (blW perm ; Wu ; Wv)
    u16* KEYP  = (u16*)p; p += 6291456;   // [12][1024][256] f16
    u16* SUp   = (u16*)p; p += 524288;    // [1024][256] f16
    u16* TVp   = (u16*)p; p += 524288;    // [1024][256] f16 (tv + f2b)
    u16* f3wbg = (u16*)p; p += 8192;      // [16][256] f16 (f3W zero-padded)

    conv_kernel<<<900, 256, 0, stream>>>(f2W, blW, f3W, blkw, f3wbg);
    gemm_st <<<dim3(8, 16),  256, 0, stream>>>(x, sW, tW, sb, tb, STb);
    gemm_kst<<<dim3(56, 16), 256, 0, stream>>>(STb, blkw, f2b, KEYP, SUp, TVp);
    fused_out<<<dim3(16, 32, 2), 256, 0, stream>>>(KEYP, STb, SUp, TVp, f3wbg, f3b, out);
}

// Round 8
// 46.435 us; speedup vs baseline: 1.2231x; 1.1215x over previous
//
#include <hip/hip_runtime.h>
#include <hip/hip_bf16.h>

// B=2, L=512, H_IN=768, E=256, N=12. M = B*L = 1024.
// out[b,i,n,j] = sum_e key[b,i,e,n]*t[b,j,e]
//             + sum_e relu(su[b,i,e]+tv[b,j,e]+f2b[e])*f3W[n,e] + f3b[n]
// All intermediates fp16.

typedef unsigned short u16;
typedef __attribute__((ext_vector_type(8))) short    s16x8;
typedef __attribute__((ext_vector_type(8))) _Float16 f16x8;
typedef __attribute__((ext_vector_type(4))) float    f32x4;

__device__ inline u16 f2h(float f) { return __builtin_bit_cast(u16, (_Float16)f); }

__device__ inline s16x8 cvt2(float4 a, float4 b) {
    f16x8 h;
    h[0] = (_Float16)a.x; h[1] = (_Float16)a.y; h[2] = (_Float16)a.z; h[3] = (_Float16)a.w;
    h[4] = (_Float16)b.x; h[5] = (_Float16)b.y; h[6] = (_Float16)b.z; h[7] = (_Float16)b.w;
    return __builtin_bit_cast(s16x8, h);
}

__device__ inline f32x4 mfma_f16(s16x8 a, s16x8 b, f32x4 c) {
    return __builtin_amdgcn_mfma_f32_16x16x32_f16(
        __builtin_bit_cast(f16x8, a), __builtin_bit_cast(f16x8, b), c, 0, 0, 0);
}
__device__ inline f32x4 mfma_f16v(f16x8 a, s16x8 b, f32x4 c) {
    return __builtin_amdgcn_mfma_f32_16x16x32_f16(a, __builtin_bit_cast(f16x8, b), c, 0, 0, 0);
}

// ---------------- prep kernel: blocks 0..255 = s|t GEMM (64x32 tiles);
//                  blocks 256..1155 = weight conversion/permutation ----------------
// blkw [3584][256]: rows 0..3071 perm(blW), 3072..3327 Wu, 3328..3583 Wv. f3wb [16][256].
__global__ __launch_bounds__(256, 2)
void prep_kernel(const float* __restrict__ x, const float* __restrict__ sW,
                 const float* __restrict__ tW, const float* __restrict__ sb,
                 const float* __restrict__ tb, const float* __restrict__ f2W,
                 const float* __restrict__ blW, const float* __restrict__ f3W,
                 u16* __restrict__ STb, u16* __restrict__ blkw, u16* __restrict__ f3wb)
{
    if (blockIdx.x >= 256) {
        // ---- conversion body ----
        int idx = (blockIdx.x - 256) * 256 + threadIdx.x;
        float4 v;
        u16* dst;
        if (idx < 229376) {
            int i4 = idx * 4;
            int r = i4 >> 8, k = i4 & 255;
            const float* src;
            if (r < 3072)      { int n = r >> 8, e = r & 255; src = &blW[(e * 12 + n) * 256 + k]; }
            else if (r < 3328) { src = &f2W[(r - 3072) * 512 + k]; }
            else               { src = &f2W[(r - 3328) * 512 + 256 + k]; }
            v = *(const float4*)src;
            dst = &blkw[i4];
        } else {
            int i4 = (idx - 229376) * 4;
            int row = i4 >> 8, e = i4 & 255;
            if (row < 12) v = *(const float4*)&f3W[row * 256 + e];
            else          v = make_float4(0.f, 0.f, 0.f, 0.f);
            dst = &f3wb[i4];
        }
        ushort4 o;
        o.x = f2h(v.x); o.y = f2h(v.y); o.z = f2h(v.z); o.w = f2h(v.w);
        *(ushort4*)dst = o;
        return;
    }
    // ---- s|t GEMM body: STb = relu(x @ [sW;tW]^T + [sb;tb]), tile 64M x 32N ----
    __shared__ u16 As[64 * 72];
    __shared__ u16 Bs[32 * 72];
    const int tid = threadIdx.x;
    const int m0 = (blockIdx.x >> 4) * 64, n0 = (blockIdx.x & 15) * 32;
    const int w = tid >> 6, l = tid & 63;
    const int wr = (w >> 1) * 32, wc = (w & 1) * 16;
    const int lr = l & 15, lg = l >> 4;
    const int srow = tid >> 2, kq = tid & 3;

    const float* ap = &x[(size_t)(m0 + srow) * 768 + kq * 16];
    const bool bstg = (tid < 128);
    const float* bp = nullptr;
    if (bstg) {
        int br = n0 + (tid >> 2);
        bp = (br < 256) ? &sW[(size_t)br * 768 + kq * 16]
                        : &tW[(size_t)(br - 256) * 768 + kq * 16];
    }
    float4 ra0 = *(const float4*)(ap + 0),  ra1 = *(const float4*)(ap + 4);
    float4 ra2 = *(const float4*)(ap + 8),  ra3 = *(const float4*)(ap + 12);
    float4 rb0, rb1, rb2, rb3;
    if (bstg) {
        rb0 = *(const float4*)(bp + 0);  rb1 = *(const float4*)(bp + 4);
        rb2 = *(const float4*)(bp + 8);  rb3 = *(const float4*)(bp + 12);
    }

    f32x4 acc[2] = {};
    for (int k0 = 0; k0 < 768; k0 += 64) {
        __syncthreads();
        *(s16x8*)&As[srow * 72 + kq * 16]     = cvt2(ra0, ra1);
        *(s16x8*)&As[srow * 72 + kq * 16 + 8] = cvt2(ra2, ra3);
        if (bstg) {
            *(s16x8*)&Bs[(tid >> 2) * 72 + kq * 16]     = cvt2(rb0, rb1);
            *(s16x8*)&Bs[(tid >> 2) * 72 + kq * 16 + 8] = cvt2(rb2, rb3);
        }
        __syncthreads();
        if (k0 + 64 < 768) {
            ra0 = *(const float4*)(ap + k0 + 64 + 0);  ra1 = *(const float4*)(ap + k0 + 64 + 4);
            ra2 = *(const float4*)(ap + k0 + 64 + 8);  ra3 = *(const float4*)(ap + k0 + 64 + 12);
            if (bstg) {
                rb0 = *(const float4*)(bp + k0 + 64 + 0);  rb1 = *(const float4*)(bp + k0 + 64 + 4);
                rb2 = *(const float4*)(bp + k0 + 64 + 8);  rb3 = *(const float4*)(bp + k0 + 64 + 12);
            }
        }
#pragma unroll
        for (int kk = 0; kk < 64; kk += 32) {
            s16x8 af[2], bf;
            af[0] = *(const s16x8*)&As[(wr      + lr) * 72 + kk + lg * 8];
            af[1] = *(const s16x8*)&As[(wr + 16 + lr) * 72 + kk + lg * 8];
            bf    = *(const s16x8*)&Bs[(wc      + lr) * 72 + kk + lg * 8];
            acc[0] = mfma_f16(af[0], bf, acc[0]);
            acc[1] = mfma_f16(af[1], bf, acc[1]);
        }
    }
#pragma unroll
    for (int fi = 0; fi < 2; ++fi) {
#pragma unroll
        for (int r = 0; r < 4; ++r) {
            int grow = m0 + wr + fi * 16 + lg * 4 + r;
            int gcol = n0 + wc + lr;
            float bias = (gcol < 256) ? sb[gcol] : tb[gcol - 256];
            float v = fmaxf(acc[fi][r] + bias, 0.f);
            STb[(size_t)grow * 512 + gcol] = f2h(v);
        }
    }
}

// ---------------- key+su+tv GEMM: one launch, N=3584, K=256 ----------------
__global__ __launch_bounds__(256, 4)
void gemm_kst(const u16* __restrict__ STb, const u16* __restrict__ BLKW,
              const float* __restrict__ f2b,
              u16* __restrict__ KEYP, u16* __restrict__ SUp, u16* __restrict__ TVp)
{
    __shared__ u16 As[64 * 72];
    __shared__ u16 Bs[64 * 72];
    const int tid = threadIdx.x;
    const int m0 = blockIdx.y * 64, n0 = blockIdx.x * 64;
    const int w = tid >> 6, l = tid & 63;
    const int wr = (w >> 1) * 32, wc = (w & 1) * 32;
    const int lr = l & 15, lg = l >> 4;
    const int srow = tid >> 2, kq = tid & 3;

    const u16* A = STb + (n0 >= 3328 ? 256 : 0);
    const u16* ap = &A[(size_t)(m0 + srow) * 512];
    const u16* bp = &BLKW[(size_t)(n0 + srow) * 256];
    s16x8 ra0 = *(const s16x8*)&ap[kq * 8];
    s16x8 ra1 = *(const s16x8*)&ap[(kq + 4) * 8];
    s16x8 rb0 = *(const s16x8*)&bp[kq * 8];
    s16x8 rb1 = *(const s16x8*)&bp[(kq + 4) * 8];

    f32x4 acc[2][2] = {};
    for (int k0 = 0; k0 < 256; k0 += 64) {
        __syncthreads();
        *(s16x8*)&As[srow * 72 + kq * 8]       = ra0;
        *(s16x8*)&As[srow * 72 + (kq + 4) * 8] = ra1;
        *(s16x8*)&Bs[srow * 72 + kq * 8]       = rb0;
        *(s16x8*)&Bs[srow * 72 + (kq + 4) * 8] = rb1;
        __syncthreads();
        if (k0 + 64 < 256) {
            ra0 = *(const s16x8*)&ap[k0 + 64 + kq * 8];
            ra1 = *(const s16x8*)&ap[k0 + 64 + (kq + 4) * 8];
            rb0 = *(const s16x8*)&bp[k0 + 64 + kq * 8];
            rb1 = *(const s16x8*)&bp[k0 + 64 + (kq + 4) * 8];
        }
#pragma unroll
        for (int kk = 0; kk < 64; kk += 32) {
            s16x8 af[2], bf[2];
            af[0] = *(const s16x8*)&As[(wr      + lr) * 72 + kk + lg * 8];
            af[1] = *(const s16x8*)&As[(wr + 16 + lr) * 72 + kk + lg * 8];
            bf[0] = *(const s16x8*)&Bs[(wc      + lr) * 72 + kk + lg * 8];
            bf[1] = *(const s16x8*)&Bs[(wc + 16 + lr) * 72 + kk + lg * 8];
#pragma unroll
            for (int fi = 0; fi < 2; ++fi)
#pragma unroll
                for (int fj = 0; fj < 2; ++fj)
                    acc[fi][fj] = mfma_f16(af[fi], bf[fj], acc[fi][fj]);
        }
    }
#pragma unroll
    for (int fi = 0; fi < 2; ++fi) {
#pragma unroll
        for (int fj = 0; fj < 2; ++fj) {
#pragma unroll
            for (int r = 0; r < 4; ++r) {
                int grow = m0 + wr + fi * 16 + lg * 4 + r;
                int gcol = n0 + wc + fj * 16 + lr;
                float v = acc[fi][fj][r];
                if (gcol < 3072) {
                    int n = gcol >> 8, e = gcol & 255;
                    KEYP[(size_t)n * 262144 + (size_t)grow * 256 + e] = f2h(v);
                } else if (gcol < 3328) {
                    SUp[(size_t)grow * 256 + (gcol - 3072)] = f2h(v);
                } else {
                    TVp[(size_t)grow * 256 + (gcol - 3328)] = f2h(v + f2b[gcol - 3328]);
                }
            }
        }
    }
}

// ---------------- fused output kernel (unchanged from measured 52.08 version) ----------------
__global__ __launch_bounds__(256, 4)
void fused_out(const u16* __restrict__ KEYP, const u16* __restrict__ STb,
               const u16* __restrict__ SUp, const u16* __restrict__ TVp,
               const u16* __restrict__ F3WH, const float* __restrict__ f3b,
               float* __restrict__ out)
{
    __shared__ __align__(16) char smem[30208];
    u16* lds = (u16*)smem;
    const int KEYC = 0, TC = 7680, SUC = 8960, TVC = 9600, F3C = 10880;

    const int tid = threadIdx.x;
    const int w = tid >> 6, l = tid & 63;

    // XCD-aware bijective remap (nwg=1024, 8 XCDs, 128 per XCD)
    const int lin  = blockIdx.x + (blockIdx.y << 4) + (blockIdx.z << 9);
    const int orig = (lin & 7) * 128 + (lin >> 3);
    const int j0 = (orig & 15) * 32;
    const int i0 = ((orig >> 4) & 31) * 16;
    const int b  = orig >> 9;

    const int lr = l & 15, lg = l >> 4;

    // staging descriptors (1088 granules of 16B; rr=4 only for tid<64)
    const u16* sb_[5]; int do_[5];
#pragma unroll
    for (int rr = 0; rr < 5; ++rr) {
        int g = tid + 256 * rr;
        const u16* s = nullptr; int d = 0;
        if (g < 768) {
            int n = g >> 6, ii = (g >> 2) & 15, qq = g & 3;
            s = KEYP + (size_t)n * 262144 + (size_t)(b * 512 + i0 + ii) * 256 + qq * 8;
            d = KEYC + (n * 16 + ii) * 40 + qq * 8;
        } else if (g < 896) {
            int q = g - 768, jj = q >> 2, qq = q & 3;
            s = STb + (size_t)(b * 512 + j0 + jj) * 512 + 256 + qq * 8;
            d = TC + jj * 40 + qq * 8;
        } else if (g < 960) {
            int q = g - 896, ii = q >> 2, qq = q & 3;
            s = SUp + (size_t)(b * 512 + i0 + ii) * 256 + qq * 8;
            d = SUC + ii * 40 + qq * 8;
        } else {
            int q = g - 960, jj = q >> 2, qq = q & 3;
            s = TVp + (size_t)(b * 512 + j0 + jj) * 256 + qq * 8;
            d = TVC + jj * 40 + qq * 8;
        }
        sb_[rr] = s; do_[rr] = d;
    }
    const bool v4 = (tid < 64);

    // f3c staged once
#pragma unroll
    for (int rr = 0; rr < 2; ++rr) {
        int g = tid + 256 * rr;
        int row = g >> 5, qq = g & 31;
        *(s16x8*)&lds[F3C + row * 264 + qq * 8] = *(const s16x8*)&F3WH[row * 256 + qq * 8];
    }

    s16x8 st0, st1, st2, st3, st4 = {};
    f32x4 acc1[3][2] = {};
    f32x4 acc2[8]    = {};

    st0 = *(const s16x8*)(sb_[0]);
    st1 = *(const s16x8*)(sb_[1]);
    st2 = *(const s16x8*)(sb_[2]);
    st3 = *(const s16x8*)(sb_[3]);
    if (v4) st4 = *(const s16x8*)(sb_[4]);

    for (int it = 0; it < 8; ++it) {
        const int e0 = it * 32;
        __syncthreads();
        *(s16x8*)&lds[do_[0]] = st0;
        *(s16x8*)&lds[do_[1]] = st1;
        *(s16x8*)&lds[do_[2]] = st2;
        *(s16x8*)&lds[do_[3]] = st3;
        if (v4) *(s16x8*)&lds[do_[4]] = st4;
        __syncthreads();
        if (it < 7) {
            st0 = *(const s16x8*)(sb_[0] + e0 + 32);
            st1 = *(const s16x8*)(sb_[1] + e0 + 32);
            st2 = *(const s16x8*)(sb_[2] + e0 + 32);
            st3 = *(const s16x8*)(sb_[3] + e0 + 32);
            if (v4) st4 = *(const s16x8*)(sb_[4] + e0 + 32);
        }
        // ---- out1: 6 mfma ----
        s16x8 tf0 = *(const s16x8*)&lds[TC + lr * 40 + lg * 8];
        s16x8 tf1 = *(const s16x8*)&lds[TC + (16 + lr) * 40 + lg * 8];
#pragma unroll
        for (int a = 0; a < 3; ++a) {
            int n = 3 * w + a;
            s16x8 kf = *(const s16x8*)&lds[KEYC + (n * 16 + lr) * 40 + lg * 8];
            acc1[a][0] = mfma_f16(kf, tf0, acc1[a][0]);
            acc1[a][1] = mfma_f16(kf, tf1, acc1[a][1]);
        }
        // ---- out2: packed-f16 h + 8 mfma ----
        f16x8 sv = __builtin_bit_cast(f16x8, *(const s16x8*)&lds[SUC + lr * 40 + lg * 8]);
        s16x8 f3fr = *(const s16x8*)&lds[F3C + lr * 264 + e0 + lg * 8];
#pragma unroll
        for (int jj = 0; jj < 8; ++jj) {
            int j = w * 8 + jj;
            f16x8 tv8 = __builtin_bit_cast(f16x8, *(const s16x8*)&lds[TVC + j * 40 + lg * 8]);
            f16x8 hv = sv + tv8;
#pragma unroll
            for (int q = 0; q < 8; ++q)
                hv[q] = hv[q] > (_Float16)0.f ? hv[q] : (_Float16)0.f;
            acc2[jj] = mfma_f16v(hv, f3fr, acc2[jj]);
        }
    }

    // ---- merge out2 into out1 layout via LDS (overlay), then store ----
    __syncthreads();
    float* mg = (float*)smem;   // [12] x stride 580 f32; i stride 36
    if (lr < 12) {
#pragma unroll
        for (int r = 0; r < 4; ++r) {
            int i = lg * 4 + r;
            f32x4 v0, v1;
            v0[0] = acc2[0][r]; v0[1] = acc2[1][r]; v0[2] = acc2[2][r]; v0[3] = acc2[3][r];
            v1[0] = acc2[4][r]; v1[1] = acc2[5][r]; v1[2] = acc2[6][r]; v1[3] = acc2[7][r];
            *(f32x4*)&mg[lr * 580 + i * 36 + w * 8]     = v0;
            *(f32x4*)&mg[lr * 580 + i * 36 + w * 8 + 4] = v1;
        }
    }
    __syncthreads();
#pragma unroll
    for (int a = 0; a < 3; ++a) {
        int n = 3 * w + a;
        float fb = f3b[n];
#pragma unroll
        for (int fj = 0; fj < 2; ++fj) {
            int j = fj * 16 + lr;
#pragma unroll
            for (int r = 0; r < 4; ++r) {
                int i = lg * 4 + r;
                float vv = acc1[a][fj][r] + mg[n * 580 + i * 36 + j] + fb;
                out[(((size_t)(b * 512 + i0 + i)) * 12 + n) * 512 + j0 + j] = vv;
            }
        }
    }
}

extern "C" void kernel_launch(void* const* d_in, const int* in_sizes, int n_in,
                              void* d_out, int out_size, void* d_ws, size_t ws_size,
                              hipStream_t stream)
{
    const float* x   = (const float*)d_in[0];
    const float* sW  = (const float*)d_in[1];
    const float* sb  = (const float*)d_in[2];
    const float* tW  = (const float*)d_in[3];
    const float* tb  = (const float*)d_in[4];
    const float* f2W = (const float*)d_in[5];
    const float* f2b = (const float*)d_in[6];
    const float* f3W = (const float*)d_in[7];
    const float* f3b = (const float*)d_in[8];
    const float* blW = (const float*)d_in[9];
    float* out = (float*)d_out;

    char* p = (char*)d_ws;
    u16* STb   = (u16*)p; p += 1048576;   // [1024][512] f16 (s|t)
    u16* blkw  = (u16*)p; p += 1835008;   // [3584][256] f16 (blW perm ; Wu ; Wv)
    u16* KEYP  = (u16*)p; p += 6291456;   // [12][1024][256] f16
    u16* SUp   = (u16*)p; p += 524288;    // [1024][256] f16
    u16* TVp   = (u16*)p; p += 524288;    // [1024][256] f16 (tv + f2b)
    u16* f3wbg = (u16*)p; p += 8192;      // [16][256] f16 (f3W zero-padded)

    prep_kernel<<<1156, 256, 0, stream>>>(x, sW, tW, sb, tb, f2W, blW, f3W,
                                          STb, blkw, f3wbg);
    gemm_kst<<<dim3(56, 16), 256, 0, stream>>>(STb, blkw, f2b, KEYP, SUp, TVp);
    fused_out<<<dim3(16, 32, 2), 256, 0, stream>>>(KEYP, STb, SUp, TVp, f3wbg, f3b, out);
}

// Round 9
// 43.476 us; speedup vs baseline: 1.3064x; 1.0681x over previous
//
#include <hip/hip_runtime.h>
#include <hip/hip_bf16.h>

// B=2, L=512, H_IN=768, E=256, N=12. M = B*L = 1024.
// out[b,i,n,j] = sum_e key[b,i,e,n]*t[b,j,e]
//             + sum_e relu(su[b,i,e]+tv[b,j,e]+f2b[e])*f3W[n,e] + f3b[n]
// All intermediates fp16. key stored in MFMA-fragment order (KEYF) so fused_out
// loads it register-direct with coalesced 1KB/wave global loads (no LDS round-trip).

typedef unsigned short u16;
typedef __attribute__((ext_vector_type(8))) short    s16x8;
typedef __attribute__((ext_vector_type(8))) _Float16 f16x8;
typedef __attribute__((ext_vector_type(4))) float    f32x4;

__device__ inline u16 f2h(float f) { return __builtin_bit_cast(u16, (_Float16)f); }

__device__ inline s16x8 cvt2(float4 a, float4 b) {
    f16x8 h;
    h[0] = (_Float16)a.x; h[1] = (_Float16)a.y; h[2] = (_Float16)a.z; h[3] = (_Float16)a.w;
    h[4] = (_Float16)b.x; h[5] = (_Float16)b.y; h[6] = (_Float16)b.z; h[7] = (_Float16)b.w;
    return __builtin_bit_cast(s16x8, h);
}

__device__ inline f32x4 mfma_f16(s16x8 a, s16x8 b, f32x4 c) {
    return __builtin_amdgcn_mfma_f32_16x16x32_f16(
        __builtin_bit_cast(f16x8, a), __builtin_bit_cast(f16x8, b), c, 0, 0, 0);
}
__device__ inline f32x4 mfma_f16v(f16x8 a, s16x8 b, f32x4 c) {
    return __builtin_amdgcn_mfma_f32_16x16x32_f16(a, __builtin_bit_cast(f16x8, b), c, 0, 0, 0);
}

// ---------------- prep kernel: blocks 0..255 = s|t GEMM (64x32 tiles);
//                  blocks 256..1155 = weight conversion/permutation ----------------
__global__ __launch_bounds__(256, 2)
void prep_kernel(const float* __restrict__ x, const float* __restrict__ sW,
                 const float* __restrict__ tW, const float* __restrict__ sb,
                 const float* __restrict__ tb, const float* __restrict__ f2W,
                 const float* __restrict__ blW, const float* __restrict__ f3W,
                 u16* __restrict__ STb, u16* __restrict__ blkw, u16* __restrict__ f3wb)
{
    if (blockIdx.x >= 256) {
        int idx = (blockIdx.x - 256) * 256 + threadIdx.x;
        float4 v;
        u16* dst;
        if (idx < 229376) {
            int i4 = idx * 4;
            int r = i4 >> 8, k = i4 & 255;
            const float* src;
            if (r < 3072)      { int n = r >> 8, e = r & 255; src = &blW[(e * 12 + n) * 256 + k]; }
            else if (r < 3328) { src = &f2W[(r - 3072) * 512 + k]; }
            else               { src = &f2W[(r - 3328) * 512 + 256 + k]; }
            v = *(const float4*)src;
            dst = &blkw[i4];
        } else {
            int i4 = (idx - 229376) * 4;
            int row = i4 >> 8, e = i4 & 255;
            if (row < 12) v = *(const float4*)&f3W[row * 256 + e];
            else          v = make_float4(0.f, 0.f, 0.f, 0.f);
            dst = &f3wb[i4];
        }
        ushort4 o;
        o.x = f2h(v.x); o.y = f2h(v.y); o.z = f2h(v.z); o.w = f2h(v.w);
        *(ushort4*)dst = o;
        return;
    }
    // ---- s|t GEMM body: STb = relu(x @ [sW;tW]^T + [sb;tb]), tile 64M x 32N ----
    __shared__ u16 As[64 * 72];
    __shared__ u16 Bs[32 * 72];
    const int tid = threadIdx.x;
    const int m0 = (blockIdx.x >> 4) * 64, n0 = (blockIdx.x & 15) * 32;
    const int w = tid >> 6, l = tid & 63;
    const int wr = (w >> 1) * 32, wc = (w & 1) * 16;
    const int lr = l & 15, lg = l >> 4;
    const int srow = tid >> 2, kq = tid & 3;

    const float* ap = &x[(size_t)(m0 + srow) * 768 + kq * 16];
    const bool bstg = (tid < 128);
    const float* bp = nullptr;
    if (bstg) {
        int br = n0 + (tid >> 2);
        bp = (br < 256) ? &sW[(size_t)br * 768 + kq * 16]
                        : &tW[(size_t)(br - 256) * 768 + kq * 16];
    }
    float4 ra0 = *(const float4*)(ap + 0),  ra1 = *(const float4*)(ap + 4);
    float4 ra2 = *(const float4*)(ap + 8),  ra3 = *(const float4*)(ap + 12);
    float4 rb0, rb1, rb2, rb3;
    if (bstg) {
        rb0 = *(const float4*)(bp + 0);  rb1 = *(const float4*)(bp + 4);
        rb2 = *(const float4*)(bp + 8);  rb3 = *(const float4*)(bp + 12);
    }

    f32x4 acc[2] = {};
    for (int k0 = 0; k0 < 768; k0 += 64) {
        __syncthreads();
        *(s16x8*)&As[srow * 72 + kq * 16]     = cvt2(ra0, ra1);
        *(s16x8*)&As[srow * 72 + kq * 16 + 8] = cvt2(ra2, ra3);
        if (bstg) {
            *(s16x8*)&Bs[(tid >> 2) * 72 + kq * 16]     = cvt2(rb0, rb1);
            *(s16x8*)&Bs[(tid >> 2) * 72 + kq * 16 + 8] = cvt2(rb2, rb3);
        }
        __syncthreads();
        if (k0 + 64 < 768) {
            ra0 = *(const float4*)(ap + k0 + 64 + 0);  ra1 = *(const float4*)(ap + k0 + 64 + 4);
            ra2 = *(const float4*)(ap + k0 + 64 + 8);  ra3 = *(const float4*)(ap + k0 + 64 + 12);
            if (bstg) {
                rb0 = *(const float4*)(bp + k0 + 64 + 0);  rb1 = *(const float4*)(bp + k0 + 64 + 4);
                rb2 = *(const float4*)(bp + k0 + 64 + 8);  rb3 = *(const float4*)(bp + k0 + 64 + 12);
            }
        }
#pragma unroll
        for (int kk = 0; kk < 64; kk += 32) {
            s16x8 af[2], bf;
            af[0] = *(const s16x8*)&As[(wr      + lr) * 72 + kk + lg * 8];
            af[1] = *(const s16x8*)&As[(wr + 16 + lr) * 72 + kk + lg * 8];
            bf    = *(const s16x8*)&Bs[(wc      + lr) * 72 + kk + lg * 8];
            acc[0] = mfma_f16(af[0], bf, acc[0]);
            acc[1] = mfma_f16(af[1], bf, acc[1]);
        }
    }
#pragma unroll
    for (int fi = 0; fi < 2; ++fi) {
#pragma unroll
        for (int r = 0; r < 4; ++r) {
            int grow = m0 + wr + fi * 16 + lg * 4 + r;
            int gcol = n0 + wc + lr;
            float bias = (gcol < 256) ? sb[gcol] : tb[gcol - 256];
            float v = fmaxf(acc[fi][r] + bias, 0.f);
            STb[(size_t)grow * 512 + gcol] = f2h(v);
        }
    }
}

// ---------------- key+su+tv GEMM: one launch, N=3584, K=256 ----------------
// key (cols<3072) written in fragment order:
// KEYF[(((n*64 + i>>4)*8 + e>>5)*64 + ((e>>3)&3)*16 + (i&15))*8 + (e&7)]
__global__ __launch_bounds__(256, 4)
void gemm_kst(const u16* __restrict__ STb, const u16* __restrict__ BLKW,
              const float* __restrict__ f2b,
              u16* __restrict__ KEYF, u16* __restrict__ SUp, u16* __restrict__ TVp)
{
    __shared__ u16 As[64 * 72];
    __shared__ u16 Bs[64 * 72];
    const int tid = threadIdx.x;
    const int m0 = blockIdx.y * 64, n0 = blockIdx.x * 64;
    const int w = tid >> 6, l = tid & 63;
    const int wr = (w >> 1) * 32, wc = (w & 1) * 32;
    const int lr = l & 15, lg = l >> 4;
    const int srow = tid >> 2, kq = tid & 3;

    const u16* A = STb + (n0 >= 3328 ? 256 : 0);
    const u16* ap = &A[(size_t)(m0 + srow) * 512];
    const u16* bp = &BLKW[(size_t)(n0 + srow) * 256];
    s16x8 ra0 = *(const s16x8*)&ap[kq * 8];
    s16x8 ra1 = *(const s16x8*)&ap[(kq + 4) * 8];
    s16x8 rb0 = *(const s16x8*)&bp[kq * 8];
    s16x8 rb1 = *(const s16x8*)&bp[(kq + 4) * 8];

    f32x4 acc[2][2] = {};
    for (int k0 = 0; k0 < 256; k0 += 64) {
        __syncthreads();
        *(s16x8*)&As[srow * 72 + kq * 8]       = ra0;
        *(s16x8*)&As[srow * 72 + (kq + 4) * 8] = ra1;
        *(s16x8*)&Bs[srow * 72 + kq * 8]       = rb0;
        *(s16x8*)&Bs[srow * 72 + (kq + 4) * 8] = rb1;
        __syncthreads();
        if (k0 + 64 < 256) {
            ra0 = *(const s16x8*)&ap[k0 + 64 + kq * 8];
            ra1 = *(const s16x8*)&ap[k0 + 64 + (kq + 4) * 8];
            rb0 = *(const s16x8*)&bp[k0 + 64 + kq * 8];
            rb1 = *(const s16x8*)&bp[k0 + 64 + (kq + 4) * 8];
        }
#pragma unroll
        for (int kk = 0; kk < 64; kk += 32) {
            s16x8 af[2], bf[2];
            af[0] = *(const s16x8*)&As[(wr      + lr) * 72 + kk + lg * 8];
            af[1] = *(const s16x8*)&As[(wr + 16 + lr) * 72 + kk + lg * 8];
            bf[0] = *(const s16x8*)&Bs[(wc      + lr) * 72 + kk + lg * 8];
            bf[1] = *(const s16x8*)&Bs[(wc + 16 + lr) * 72 + kk + lg * 8];
#pragma unroll
            for (int fi = 0; fi < 2; ++fi)
#pragma unroll
                for (int fj = 0; fj < 2; ++fj)
                    acc[fi][fj] = mfma_f16(af[fi], bf[fj], acc[fi][fj]);
        }
    }
#pragma unroll
    for (int fi = 0; fi < 2; ++fi) {
#pragma unroll
        for (int fj = 0; fj < 2; ++fj) {
#pragma unroll
            for (int r = 0; r < 4; ++r) {
                int grow = m0 + wr + fi * 16 + lg * 4 + r;
                int gcol = n0 + wc + fj * 16 + lr;
                float v = acc[fi][fj][r];
                if (gcol < 3072) {
                    int n = gcol >> 8, e = gcol & 255;
                    int g = grow >> 4, li = grow & 15;
                    int it = e >> 5, sub = (e >> 3) & 3, eo = e & 7;
                    KEYF[((((size_t)n * 64 + g) * 8 + it) * 64 + sub * 16 + li) * 8 + eo] = f2h(v);
                } else if (gcol < 3328) {
                    SUp[(size_t)grow * 256 + (gcol - 3072)] = f2h(v);
                } else {
                    TVp[(size_t)grow * 256 + (gcol - 3328)] = f2h(v + f2b[gcol - 3328]);
                }
            }
        }
    }
}

// ---------------- fused output kernel ----------------
// grid 1024 (16 j, 32 i, 2 b) with XCD swizzle; block = 16i x 32j, 256 thr = 4 waves.
// key: register-direct coalesced loads from KEYF (fragment order). t/su/tv double-
// buffered in LDS, ONE barrier per iteration. f3 staged once.
__global__ __launch_bounds__(256, 4)
void fused_out(const u16* __restrict__ KEYF, const u16* __restrict__ STb,
               const u16* __restrict__ SUp, const u16* __restrict__ TVp,
               const u16* __restrict__ F3WH, const float* __restrict__ f3b,
               float* __restrict__ out)
{
    __shared__ __align__(16) char smem[27904];
    u16* lds = (u16*)smem;
    // u16 offsets: TC[2] @0/1280 (32x40) | SUC[2] @2560/3200 (16x40)
    //              TVC[2] @3840/5120 (32x40) | F3C @6400 (16x264, ends 10624 = 21248B)
    const int TC0 = 0, SUC0 = 2560, TVC0 = 3840, F3C = 6400;

    const int tid = threadIdx.x;
    const int w = tid >> 6, l = tid & 63;

    // XCD-aware bijective remap (nwg=1024, 8 XCDs, 128 per XCD)
    const int lin  = blockIdx.x + (blockIdx.y << 4) + (blockIdx.z << 9);
    const int orig = (lin & 7) * 128 + (lin >> 3);
    const int j0 = (orig & 15) * 32;
    const int i0 = ((orig >> 4) & 31) * 16;
    const int b  = orig >> 9;

    const int lr = l & 15, lg = l >> 4;

    // staging descriptors: t (tid<128), tv (tid>=128); su extra for tid<64
    const u16* src1; int d1;
    if (tid < 128) {
        int jj = tid >> 2, qq = tid & 3;
        src1 = STb + (size_t)(b * 512 + j0 + jj) * 512 + 256 + qq * 8;
        d1 = TC0 + jj * 40 + qq * 8;
    } else {
        int q = tid - 128, jj = q >> 2, qq = q & 3;
        src1 = TVp + (size_t)(b * 512 + j0 + jj) * 256 + qq * 8;
        d1 = TVC0 + jj * 40 + qq * 8;
    }
    const u16* src2 = nullptr; int d2 = 0;
    const bool has2 = (tid < 64);
    if (has2) {
        int ii = tid >> 2, qq = tid & 3;
        src2 = SUp + (size_t)(b * 512 + i0 + ii) * 256 + qq * 8;
        d2 = SUC0 + ii * 40 + qq * 8;
    }

    // f3 staged once
#pragma unroll
    for (int rr = 0; rr < 2; ++rr) {
        int g = tid + 256 * rr;
        int row = g >> 5, qq = g & 31;
        *(s16x8*)&lds[F3C + row * 264 + qq * 8] = *(const s16x8*)&F3WH[row * 256 + qq * 8];
    }

    // key fragment bases (register-direct): wave w owns n = 3w..3w+2
    const int gblk = b * 32 + (i0 >> 4);
    const u16* kfb0 = KEYF + ((size_t)((3 * w + 0) * 64 + gblk) * 8) * 512 + l * 8;
    const u16* kfb1 = KEYF + ((size_t)((3 * w + 1) * 64 + gblk) * 8) * 512 + l * 8;
    const u16* kfb2 = KEYF + ((size_t)((3 * w + 2) * 64 + gblk) * 8) * 512 + l * 8;

    // prologue: stage iter0 into buf0, prefetch kf(it0) and regs for it1
    s16x8 r1 = *(const s16x8*)src1;
    s16x8 r2 = {};
    if (has2) r2 = *(const s16x8*)src2;
    *(s16x8*)&lds[d1] = r1;
    if (has2) *(s16x8*)&lds[d2] = r2;
    s16x8 kf0 = *(const s16x8*)kfb0;
    s16x8 kf1 = *(const s16x8*)kfb1;
    s16x8 kf2 = *(const s16x8*)kfb2;
    r1 = *(const s16x8*)(src1 + 32);
    if (has2) r2 = *(const s16x8*)(src2 + 32);
    __syncthreads();

    f32x4 acc1[3][2] = {};
    f32x4 acc2[8]    = {};

#pragma unroll
    for (int it = 0; it < 8; ++it) {
        const int cur = it & 1, nxt = cur ^ 1;
        // commit next-iter regs into the other buffer (readers use cur)
        if (it < 7) {
            *(s16x8*)&lds[d1 + nxt * 1280] = r1;
            if (has2) *(s16x8*)&lds[d2 + nxt * 640] = r2;
        }
        // ---- out1: 6 mfma (kf in regs, t from LDS) ----
        s16x8 tf0 = *(const s16x8*)&lds[TC0 + cur * 1280 + lr * 40 + lg * 8];
        s16x8 tf1 = *(const s16x8*)&lds[TC0 + cur * 1280 + (16 + lr) * 40 + lg * 8];
        acc1[0][0] = mfma_f16(kf0, tf0, acc1[0][0]);
        acc1[0][1] = mfma_f16(kf0, tf1, acc1[0][1]);
        acc1[1][0] = mfma_f16(kf1, tf0, acc1[1][0]);
        acc1[1][1] = mfma_f16(kf1, tf1, acc1[1][1]);
        acc1[2][0] = mfma_f16(kf2, tf0, acc1[2][0]);
        acc1[2][1] = mfma_f16(kf2, tf1, acc1[2][1]);
        // prefetch next kf (latency hides under out2)
        s16x8 nk0, nk1, nk2;
        if (it < 7) {
            nk0 = *(const s16x8*)(kfb0 + (it + 1) * 512);
            nk1 = *(const s16x8*)(kfb1 + (it + 1) * 512);
            nk2 = *(const s16x8*)(kfb2 + (it + 1) * 512);
        }
        // ---- out2: packed-f16 h + 8 mfma ----
        f16x8 sv = __builtin_bit_cast(f16x8,
            *(const s16x8*)&lds[SUC0 + cur * 640 + lr * 40 + lg * 8]);
        s16x8 f3fr = *(const s16x8*)&lds[F3C + lr * 264 + it * 32 + lg * 8];
#pragma unroll
        for (int jj = 0; jj < 8; ++jj) {
            int j = w * 8 + jj;
            f16x8 tv8 = __builtin_bit_cast(f16x8,
                *(const s16x8*)&lds[TVC0 + cur * 1280 + j * 40 + lg * 8]);
            f16x8 hv = sv + tv8;
#pragma unroll
            for (int q = 0; q < 8; ++q)
                hv[q] = hv[q] > (_Float16)0.f ? hv[q] : (_Float16)0.f;
            acc2[jj] = mfma_f16v(hv, f3fr, acc2[jj]);
        }
        // issue global loads for it+2
        if (it < 6) {
            r1 = *(const s16x8*)(src1 + (it + 2) * 32);
            if (has2) r2 = *(const s16x8*)(src2 + (it + 2) * 32);
        }
        if (it < 7) { kf0 = nk0; kf1 = nk1; kf2 = nk2; }
        __syncthreads();   // single barrier per iteration
    }

    // ---- merge out2 D[n=lr][i][j] into out1 layout via LDS (overlay), then store ----
    float* mg = (float*)smem;   // [12] x stride 580 f32; i stride 36
    if (lr < 12) {
#pragma unroll
        for (int r = 0; r < 4; ++r) {
            int i = lg * 4 + r;
            f32x4 v0, v1;
            v0[0] = acc2[0][r]; v0[1] = acc2[1][r]; v0[2] = acc2[2][r]; v0[3] = acc2[3][r];
            v1[0] = acc2[4][r]; v1[1] = acc2[5][r]; v1[2] = acc2[6][r]; v1[3] = acc2[7][r];
            *(f32x4*)&mg[lr * 580 + i * 36 + w * 8]     = v0;
            *(f32x4*)&mg[lr * 580 + i * 36 + w * 8 + 4] = v1;
        }
    }
    __syncthreads();
#pragma unroll
    for (int a = 0; a < 3; ++a) {
        int n = 3 * w + a;
        float fb = f3b[n];
#pragma unroll
        for (int fj = 0; fj < 2; ++fj) {
            int j = fj * 16 + lr;
#pragma unroll
            for (int r = 0; r < 4; ++r) {
                int i = lg * 4 + r;
                float vv = acc1[a][fj][r] + mg[n * 580 + i * 36 + j] + fb;
                out[(((size_t)(b * 512 + i0 + i)) * 12 + n) * 512 + j0 + j] = vv;
            }
        }
    }
}

extern "C" void kernel_launch(void* const* d_in, const int* in_sizes, int n_in,
                              void* d_out, int out_size, void* d_ws, size_t ws_size,
                              hipStream_t stream)
{
    const float* x   = (const float*)d_in[0];
    const float* sW  = (const float*)d_in[1];
    const float* sb  = (const float*)d_in[2];
    const float* tW  = (const float*)d_in[3];
    const float* tb  = (const float*)d_in[4];
    const float* f2W = (const float*)d_in[5];
    const float* f2b = (const float*)d_in[6];
    const float* f3W = (const float*)d_in[7];
    const float* f3b = (const float*)d_in[8];
    const float* blW = (const float*)d_in[9];
    float* out = (float*)d_out;

    char* p = (char*)d_ws;
    u16* STb   = (u16*)p; p += 1048576;   // [1024][512] f16 (s|t)
    u16* blkw  = (u16*)p; p += 1835008;   // [3584][256] f16 (blW perm ; Wu ; Wv)
    u16* KEYF  = (u16*)p; p += 6291456;   // [12][64][8][64][8] f16 fragment order
    u16* SUp   = (u16*)p; p += 524288;    // [1024][256] f16
    u16* TVp   = (u16*)p; p += 524288;    // [1024][256] f16 (tv + f2b)
    u16* f3wbg = (u16*)p; p += 8192;      // [16][256] f16 (f3W zero-padded)

    prep_kernel<<<1156, 256, 0, stream>>>(x, sW, tW, sb, tb, f2W, blW, f3W,
                                          STb, blkw, f3wbg);
    gemm_kst<<<dim3(56, 16), 256, 0, stream>>>(STb, blkw, f2b, KEYF, SUp, TVp);
    fused_out<<<dim3(16, 32, 2), 256, 0, stream>>>(KEYF, STb, SUp, TVp, f3wbg, f3b, out);
}

// Round 10
// 43.133 us; speedup vs baseline: 1.3167x; 1.0079x over previous
//
#include <hip/hip_runtime.h>
#include <hip/hip_bf16.h>

// B=2, L=512, H_IN=768, E=256, N=12. M = B*L = 1024.
// out[b,i,n,j] = sum_e key[b,i,e,n]*t[b,j,e]
//             + sum_e relu(su[b,i,e]+tv[b,j,e]+f2b[e])*f3W[n,e] + f3b[n]
// All intermediates fp16. key stored in MFMA-fragment order (KEYF) so fused_out
// loads it register-direct with coalesced 1KB/wave global loads (no LDS round-trip).

typedef unsigned short u16;
typedef __attribute__((ext_vector_type(8))) short    s16x8;
typedef __attribute__((ext_vector_type(8))) _Float16 f16x8;
typedef __attribute__((ext_vector_type(4))) float    f32x4;

__device__ inline u16 f2h(float f) { return __builtin_bit_cast(u16, (_Float16)f); }

__device__ inline s16x8 cvt2(float4 a, float4 b) {
    f16x8 h;
    h[0] = (_Float16)a.x; h[1] = (_Float16)a.y; h[2] = (_Float16)a.z; h[3] = (_Float16)a.w;
    h[4] = (_Float16)b.x; h[5] = (_Float16)b.y; h[6] = (_Float16)b.z; h[7] = (_Float16)b.w;
    return __builtin_bit_cast(s16x8, h);
}

__device__ inline f16x8 relu8(f16x8 v) {
#if __has_builtin(__builtin_elementwise_max)
    f16x8 z = {};
    return __builtin_elementwise_max(v, z);
#else
#pragma unroll
    for (int q = 0; q < 8; ++q) v[q] = v[q] > (_Float16)0.f ? v[q] : (_Float16)0.f;
    return v;
#endif
}

__device__ inline f32x4 mfma_f16(s16x8 a, s16x8 b, f32x4 c) {
    return __builtin_amdgcn_mfma_f32_16x16x32_f16(
        __builtin_bit_cast(f16x8, a), __builtin_bit_cast(f16x8, b), c, 0, 0, 0);
}
__device__ inline f32x4 mfma_f16v(f16x8 a, s16x8 b, f32x4 c) {
    return __builtin_amdgcn_mfma_f32_16x16x32_f16(a, __builtin_bit_cast(f16x8, b), c, 0, 0, 0);
}

// ---------------- prep kernel: blocks 0..255 = s|t GEMM (64x32 tiles);
//                  blocks 256..1155 = weight conversion/permutation ----------------
__global__ __launch_bounds__(256, 3)
void prep_kernel(const float* __restrict__ x, const float* __restrict__ sW,
                 const float* __restrict__ tW, const float* __restrict__ sb,
                 const float* __restrict__ tb, const float* __restrict__ f2W,
                 const float* __restrict__ blW, const float* __restrict__ f3W,
                 u16* __restrict__ STb, u16* __restrict__ blkw, u16* __restrict__ f3wb)
{
    if (blockIdx.x >= 256) {
        int idx = (blockIdx.x - 256) * 256 + threadIdx.x;
        float4 v;
        u16* dst;
        if (idx < 229376) {
            int i4 = idx * 4;
            int r = i4 >> 8, k = i4 & 255;
            const float* src;
            if (r < 3072)      { int n = r >> 8, e = r & 255; src = &blW[(e * 12 + n) * 256 + k]; }
            else if (r < 3328) { src = &f2W[(r - 3072) * 512 + k]; }
            else               { src = &f2W[(r - 3328) * 512 + 256 + k]; }
            v = *(const float4*)src;
            dst = &blkw[i4];
        } else {
            int i4 = (idx - 229376) * 4;
            int row = i4 >> 8, e = i4 & 255;
            if (row < 12) v = *(const float4*)&f3W[row * 256 + e];
            else          v = make_float4(0.f, 0.f, 0.f, 0.f);
            dst = &f3wb[i4];
        }
        ushort4 o;
        o.x = f2h(v.x); o.y = f2h(v.y); o.z = f2h(v.z); o.w = f2h(v.w);
        *(ushort4*)dst = o;
        return;
    }
    // ---- s|t GEMM body: STb = relu(x @ [sW;tW]^T + [sb;tb]), tile 64M x 32N ----
    __shared__ u16 As[64 * 72];
    __shared__ u16 Bs[32 * 72];
    const int tid = threadIdx.x;
    const int m0 = (blockIdx.x >> 4) * 64, n0 = (blockIdx.x & 15) * 32;
    const int w = tid >> 6, l = tid & 63;
    const int wr = (w >> 1) * 32, wc = (w & 1) * 16;
    const int lr = l & 15, lg = l >> 4;
    const int srow = tid >> 2, kq = tid & 3;

    const float* ap = &x[(size_t)(m0 + srow) * 768 + kq * 16];
    const bool bstg = (tid < 128);
    const float* bp = nullptr;
    if (bstg) {
        int br = n0 + (tid >> 2);
        bp = (br < 256) ? &sW[(size_t)br * 768 + kq * 16]
                        : &tW[(size_t)(br - 256) * 768 + kq * 16];
    }
    float4 ra0 = *(const float4*)(ap + 0),  ra1 = *(const float4*)(ap + 4);
    float4 ra2 = *(const float4*)(ap + 8),  ra3 = *(const float4*)(ap + 12);
    float4 rb0, rb1, rb2, rb3;
    if (bstg) {
        rb0 = *(const float4*)(bp + 0);  rb1 = *(const float4*)(bp + 4);
        rb2 = *(const float4*)(bp + 8);  rb3 = *(const float4*)(bp + 12);
    }

    f32x4 acc[2] = {};
    for (int k0 = 0; k0 < 768; k0 += 64) {
        __syncthreads();
        *(s16x8*)&As[srow * 72 + kq * 16]     = cvt2(ra0, ra1);
        *(s16x8*)&As[srow * 72 + kq * 16 + 8] = cvt2(ra2, ra3);
        if (bstg) {
            *(s16x8*)&Bs[(tid >> 2) * 72 + kq * 16]     = cvt2(rb0, rb1);
            *(s16x8*)&Bs[(tid >> 2) * 72 + kq * 16 + 8] = cvt2(rb2, rb3);
        }
        __syncthreads();
        if (k0 + 64 < 768) {
            ra0 = *(const float4*)(ap + k0 + 64 + 0);  ra1 = *(const float4*)(ap + k0 + 64 + 4);
            ra2 = *(const float4*)(ap + k0 + 64 + 8);  ra3 = *(const float4*)(ap + k0 + 64 + 12);
            if (bstg) {
                rb0 = *(const float4*)(bp + k0 + 64 + 0);  rb1 = *(const float4*)(bp + k0 + 64 + 4);
                rb2 = *(const float4*)(bp + k0 + 64 + 8);  rb3 = *(const float4*)(bp + k0 + 64 + 12);
            }
        }
#pragma unroll
        for (int kk = 0; kk < 64; kk += 32) {
            s16x8 af[2], bf;
            af[0] = *(const s16x8*)&As[(wr      + lr) * 72 + kk + lg * 8];
            af[1] = *(const s16x8*)&As[(wr + 16 + lr) * 72 + kk + lg * 8];
            bf    = *(const s16x8*)&Bs[(wc      + lr) * 72 + kk + lg * 8];
            acc[0] = mfma_f16(af[0], bf, acc[0]);
            acc[1] = mfma_f16(af[1], bf, acc[1]);
        }
    }
#pragma unroll
    for (int fi = 0; fi < 2; ++fi) {
#pragma unroll
        for (int r = 0; r < 4; ++r) {
            int grow = m0 + wr + fi * 16 + lg * 4 + r;
            int gcol = n0 + wc + lr;
            float bias = (gcol < 256) ? sb[gcol] : tb[gcol - 256];
            float v = fmaxf(acc[fi][r] + bias, 0.f);
            STb[(size_t)grow * 512 + gcol] = f2h(v);
        }
    }
}

// ---------------- key+su+tv GEMM: one launch, N=3584, K=256 ----------------
// key (cols<3072) written in fragment order:
// KEYF[(((n*64 + i>>4)*8 + e>>5)*64 + ((e>>3)&3)*16 + (i&15))*8 + (e&7)]
__global__ __launch_bounds__(256, 6)
void gemm_kst(const u16* __restrict__ STb, const u16* __restrict__ BLKW,
              const float* __restrict__ f2b,
              u16* __restrict__ KEYF, u16* __restrict__ SUp, u16* __restrict__ TVp)
{
    __shared__ u16 As[64 * 72];
    __shared__ u16 Bs[64 * 72];
    const int tid = threadIdx.x;
    const int m0 = blockIdx.y * 64, n0 = blockIdx.x * 64;
    const int w = tid >> 6, l = tid & 63;
    const int wr = (w >> 1) * 32, wc = (w & 1) * 32;
    const int lr = l & 15, lg = l >> 4;
    const int srow = tid >> 2, kq = tid & 3;

    const u16* A = STb + (n0 >= 3328 ? 256 : 0);
    const u16* ap = &A[(size_t)(m0 + srow) * 512];
    const u16* bp = &BLKW[(size_t)(n0 + srow) * 256];
    s16x8 ra0 = *(const s16x8*)&ap[kq * 8];
    s16x8 ra1 = *(const s16x8*)&ap[(kq + 4) * 8];
    s16x8 rb0 = *(const s16x8*)&bp[kq * 8];
    s16x8 rb1 = *(const s16x8*)&bp[(kq + 4) * 8];

    f32x4 acc[2][2] = {};
    for (int k0 = 0; k0 < 256; k0 += 64) {
        __syncthreads();
        *(s16x8*)&As[srow * 72 + kq * 8]       = ra0;
        *(s16x8*)&As[srow * 72 + (kq + 4) * 8] = ra1;
        *(s16x8*)&Bs[srow * 72 + kq * 8]       = rb0;
        *(s16x8*)&Bs[srow * 72 + (kq + 4) * 8] = rb1;
        __syncthreads();
        if (k0 + 64 < 256) {
            ra0 = *(const s16x8*)&ap[k0 + 64 + kq * 8];
            ra1 = *(const s16x8*)&ap[k0 + 64 + (kq + 4) * 8];
            rb0 = *(const s16x8*)&bp[k0 + 64 + kq * 8];
            rb1 = *(const s16x8*)&bp[k0 + 64 + (kq + 4) * 8];
        }
#pragma unroll
        for (int kk = 0; kk < 64; kk += 32) {
            s16x8 af[2], bf[2];
            af[0] = *(const s16x8*)&As[(wr      + lr) * 72 + kk + lg * 8];
            af[1] = *(const s16x8*)&As[(wr + 16 + lr) * 72 + kk + lg * 8];
            bf[0] = *(const s16x8*)&Bs[(wc      + lr) * 72 + kk + lg * 8];
            bf[1] = *(const s16x8*)&Bs[(wc + 16 + lr) * 72 + kk + lg * 8];
#pragma unroll
            for (int fi = 0; fi < 2; ++fi)
#pragma unroll
                for (int fj = 0; fj < 2; ++fj)
                    acc[fi][fj] = mfma_f16(af[fi], bf[fj], acc[fi][fj]);
        }
    }
#pragma unroll
    for (int fi = 0; fi < 2; ++fi) {
#pragma unroll
        for (int fj = 0; fj < 2; ++fj) {
#pragma unroll
            for (int r = 0; r < 4; ++r) {
                int grow = m0 + wr + fi * 16 + lg * 4 + r;
                int gcol = n0 + wc + fj * 16 + lr;
                float v = acc[fi][fj][r];
                if (gcol < 3072) {
                    int n = gcol >> 8, e = gcol & 255;
                    int g = grow >> 4, li = grow & 15;
                    int it = e >> 5, sub = (e >> 3) & 3, eo = e & 7;
                    KEYF[((((size_t)n * 64 + g) * 8 + it) * 64 + sub * 16 + li) * 8 + eo] = f2h(v);
                } else if (gcol < 3328) {
                    SUp[(size_t)grow * 256 + (gcol - 3072)] = f2h(v);
                } else {
                    TVp[(size_t)grow * 256 + (gcol - 3328)] = f2h(v + f2b[gcol - 3328]);
                }
            }
        }
    }
}

// ---------------- fused output kernel ----------------
// grid 1024 (16 j, 32 i, 2 b) with XCD swizzle; block = 16i x 32j, 256 thr = 4 waves.
// key: register-direct coalesced loads from KEYF (fragment order). t/su/tv double-
// buffered in LDS, ONE barrier per iteration. f3 staged once.
__global__ __launch_bounds__(256, 4)
void fused_out(const u16* __restrict__ KEYF, const u16* __restrict__ STb,
               const u16* __restrict__ SUp, const u16* __restrict__ TVp,
               const u16* __restrict__ F3WH, const float* __restrict__ f3b,
               float* __restrict__ out)
{
    __shared__ __align__(16) char smem[27904];
    u16* lds = (u16*)smem;
    const int TC0 = 0, SUC0 = 2560, TVC0 = 3840, F3C = 6400;

    const int tid = threadIdx.x;
    const int w = tid >> 6, l = tid & 63;

    // XCD-aware bijective remap (nwg=1024, 8 XCDs, 128 per XCD)
    const int lin  = blockIdx.x + (blockIdx.y << 4) + (blockIdx.z << 9);
    const int orig = (lin & 7) * 128 + (lin >> 3);
    const int j0 = (orig & 15) * 32;
    const int i0 = ((orig >> 4) & 31) * 16;
    const int b  = orig >> 9;

    const int lr = l & 15, lg = l >> 4;

    // staging descriptors: t (tid<128), tv (tid>=128); su extra for tid<64
    const u16* src1; int d1;
    if (tid < 128) {
        int jj = tid >> 2, qq = tid & 3;
        src1 = STb + (size_t)(b * 512 + j0 + jj) * 512 + 256 + qq * 8;
        d1 = TC0 + jj * 40 + qq * 8;
    } else {
        int q = tid - 128, jj = q >> 2, qq = q & 3;
        src1 = TVp + (size_t)(b * 512 + j0 + jj) * 256 + qq * 8;
        d1 = TVC0 + jj * 40 + qq * 8;
    }
    const u16* src2 = nullptr; int d2 = 0;
    const bool has2 = (tid < 64);
    if (has2) {
        int ii = tid >> 2, qq = tid & 3;
        src2 = SUp + (size_t)(b * 512 + i0 + ii) * 256 + qq * 8;
        d2 = SUC0 + ii * 40 + qq * 8;
    }

    // f3 staged once
#pragma unroll
    for (int rr = 0; rr < 2; ++rr) {
        int g = tid + 256 * rr;
        int row = g >> 5, qq = g & 31;
        *(s16x8*)&lds[F3C + row * 264 + qq * 8] = *(const s16x8*)&F3WH[row * 256 + qq * 8];
    }

    // key fragment bases (register-direct): wave w owns n = 3w..3w+2
    const int gblk = b * 32 + (i0 >> 4);
    const u16* kfb0 = KEYF + ((size_t)((3 * w + 0) * 64 + gblk) * 8) * 512 + l * 8;
    const u16* kfb1 = KEYF + ((size_t)((3 * w + 1) * 64 + gblk) * 8) * 512 + l * 8;
    const u16* kfb2 = KEYF + ((size_t)((3 * w + 2) * 64 + gblk) * 8) * 512 + l * 8;

    // prologue: stage iter0 into buf0, prefetch kf(it0) and regs for it1
    s16x8 r1 = *(const s16x8*)src1;
    s16x8 r2 = {};
    if (has2) r2 = *(const s16x8*)src2;
    *(s16x8*)&lds[d1] = r1;
    if (has2) *(s16x8*)&lds[d2] = r2;
    s16x8 kf0 = *(const s16x8*)kfb0;
    s16x8 kf1 = *(const s16x8*)kfb1;
    s16x8 kf2 = *(const s16x8*)kfb2;
    r1 = *(const s16x8*)(src1 + 32);
    if (has2) r2 = *(const s16x8*)(src2 + 32);
    __syncthreads();

    f32x4 acc1[3][2] = {};
    f32x4 acc2[8]    = {};

#pragma unroll
    for (int it = 0; it < 8; ++it) {
        const int cur = it & 1, nxt = cur ^ 1;
        // commit next-iter regs into the other buffer (readers use cur)
        if (it < 7) {
            *(s16x8*)&lds[d1 + nxt * 1280] = r1;
            if (has2) *(s16x8*)&lds[d2 + nxt * 640] = r2;
        }
        // ---- out1: 6 mfma (kf in regs, t from LDS) ----
        s16x8 tf0 = *(const s16x8*)&lds[TC0 + cur * 1280 + lr * 40 + lg * 8];
        s16x8 tf1 = *(const s16x8*)&lds[TC0 + cur * 1280 + (16 + lr) * 40 + lg * 8];
        acc1[0][0] = mfma_f16(kf0, tf0, acc1[0][0]);
        acc1[0][1] = mfma_f16(kf0, tf1, acc1[0][1]);
        acc1[1][0] = mfma_f16(kf1, tf0, acc1[1][0]);
        acc1[1][1] = mfma_f16(kf1, tf1, acc1[1][1]);
        acc1[2][0] = mfma_f16(kf2, tf0, acc1[2][0]);
        acc1[2][1] = mfma_f16(kf2, tf1, acc1[2][1]);
        // prefetch next kf (latency hides under out2)
        s16x8 nk0, nk1, nk2;
        if (it < 7) {
            nk0 = *(const s16x8*)(kfb0 + (it + 1) * 512);
            nk1 = *(const s16x8*)(kfb1 + (it + 1) * 512);
            nk2 = *(const s16x8*)(kfb2 + (it + 1) * 512);
        }
        // ---- out2: packed-f16 h + 8 mfma ----
        f16x8 sv = __builtin_bit_cast(f16x8,
            *(const s16x8*)&lds[SUC0 + cur * 640 + lr * 40 + lg * 8]);
        s16x8 f3fr = *(const s16x8*)&lds[F3C + lr * 264 + it * 32 + lg * 8];
#pragma unroll
        for (int jj = 0; jj < 8; ++jj) {
            int j = w * 8 + jj;
            f16x8 tv8 = __builtin_bit_cast(f16x8,
                *(const s16x8*)&lds[TVC0 + cur * 1280 + j * 40 + lg * 8]);
            f16x8 hv = relu8(sv + tv8);
            acc2[jj] = mfma_f16v(hv, f3fr, acc2[jj]);
        }
        // issue global loads for it+2
        if (it < 6) {
            r1 = *(const s16x8*)(src1 + (it + 2) * 32);
            if (has2) r2 = *(const s16x8*)(src2 + (it + 2) * 32);
        }
        if (it < 7) { kf0 = nk0; kf1 = nk1; kf2 = nk2; }
        __syncthreads();   // single barrier per iteration
    }

    // ---- merge out2 D[n=lr][i][j] into out1 layout via LDS (overlay), then store ----
    float* mg = (float*)smem;   // [12] x stride 580 f32; i stride 36
    if (lr < 12) {
#pragma unroll
        for (int r = 0; r < 4; ++r) {
            int i = lg * 4 + r;
            f32x4 v0, v1;
            v0[0] = acc2[0][r]; v0[1] = acc2[1][r]; v0[2] = acc2[2][r]; v0[3] = acc2[3][r];
            v1[0] = acc2[4][r]; v1[1] = acc2[5][r]; v1[2] = acc2[6][r]; v1[3] = acc2[7][r];
            *(f32x4*)&mg[lr * 580 + i * 36 + w * 8]     = v0;
            *(f32x4*)&mg[lr * 580 + i * 36 + w * 8 + 4] = v1;
        }
    }
    __syncthreads();
#pragma unroll
    for (int a = 0; a < 3; ++a) {
        int n = 3 * w + a;
        float fb = f3b[n];
#pragma unroll
        for (int fj = 0; fj < 2; ++fj) {
            int j = fj * 16 + lr;
#pragma unroll
            for (int r = 0; r < 4; ++r) {
                int i = lg * 4 + r;
                float vv = acc1[a][fj][r] + mg[n * 580 + i * 36 + j] + fb;
                out[(((size_t)(b * 512 + i0 + i)) * 12 + n) * 512 + j0 + j] = vv;
            }
        }
    }
}

extern "C" void kernel_launch(void* const* d_in, const int* in_sizes, int n_in,
                              void* d_out, int out_size, void* d_ws, size_t ws_size,
                              hipStream_t stream)
{
    const float* x   = (const float*)d_in[0];
    const float* sW  = (const float*)d_in[1];
    const float* sb  = (const float*)d_in[2];
    const float* tW  = (const float*)d_in[3];
    const float* tb  = (const float*)d_in[4];
    const float* f2W = (const float*)d_in[5];
    const float* f2b = (const float*)d_in[6];
    const float* f3W = (const float*)d_in[7];
    const float* f3b = (const float*)d_in[8];
    const float* blW = (const float*)d_in[9];
    float* out = (float*)d_out;

    char* p = (char*)d_ws;
    u16* STb   = (u16*)p; p += 1048576;   // [1024][512] f16 (s|t)
    u16* blkw  = (u16*)p; p += 1835008;   // [3584][256] f16 (blW perm ; Wu ; Wv)
    u16* KEYF  = (u16*)p; p += 6291456;   // [12][64][8][64][8] f16 fragment order
    u16* SUp   = (u16*)p; p += 524288;    // [1024][256] f16
    u16* TVp   = (u16*)p; p += 524288;    // [1024][256] f16 (tv + f2b)
    u16* f3wbg = (u16*)p; p += 8192;      // [16][256] f16 (f3W zero-padded)

    prep_kernel<<<1156, 256, 0, stream>>>(x, sW, tW, sb, tb, f2W, blW, f3W,
                                          STb, blkw, f3wbg);
    gemm_kst<<<dim3(56, 16), 256, 0, stream>>>(STb, blkw, f2b, KEYF, SUp, TVp);
    fused_out<<<dim3(16, 32, 2), 256, 0, stream>>>(KEYF, STb, SUp, TVp, f3wbg, f3b, out);
}

// Round 11
// 42.707 us; speedup vs baseline: 1.3299x; 1.0100x over previous
//
#include <hip/hip_runtime.h>
#include <hip/hip_bf16.h>

// B=2, L=512, H_IN=768, E=256, N=12. M = B*L = 1024.
// out[b,i,n,j] = sum_e key[b,i,e,n]*t[b,j,e]
//             + sum_e relu(su[b,i,e]+tv[b,j,e]+f2b[e])*f3W[n,e] + f3b[n]
// All intermediates fp16. key stored in MFMA-fragment order (KEYF) so fused_out
// loads it register-direct with coalesced 1KB/wave global loads (no LDS round-trip).
// GEMMs use bijective XCD-aware block remaps so reused operands stay L2-resident.

typedef unsigned short u16;
typedef __attribute__((ext_vector_type(8))) short    s16x8;
typedef __attribute__((ext_vector_type(8))) _Float16 f16x8;
typedef __attribute__((ext_vector_type(4))) float    f32x4;

__device__ inline u16 f2h(float f) { return __builtin_bit_cast(u16, (_Float16)f); }

__device__ inline s16x8 cvt2(float4 a, float4 b) {
    f16x8 h;
    h[0] = (_Float16)a.x; h[1] = (_Float16)a.y; h[2] = (_Float16)a.z; h[3] = (_Float16)a.w;
    h[4] = (_Float16)b.x; h[5] = (_Float16)b.y; h[6] = (_Float16)b.z; h[7] = (_Float16)b.w;
    return __builtin_bit_cast(s16x8, h);
}

__device__ inline f16x8 relu8(f16x8 v) {
#if __has_builtin(__builtin_elementwise_max)
    f16x8 z = {};
    return __builtin_elementwise_max(v, z);
#else
#pragma unroll
    for (int q = 0; q < 8; ++q) v[q] = v[q] > (_Float16)0.f ? v[q] : (_Float16)0.f;
    return v;
#endif
}

__device__ inline f32x4 mfma_f16(s16x8 a, s16x8 b, f32x4 c) {
    return __builtin_amdgcn_mfma_f32_16x16x32_f16(
        __builtin_bit_cast(f16x8, a), __builtin_bit_cast(f16x8, b), c, 0, 0, 0);
}
__device__ inline f32x4 mfma_f16v(f16x8 a, s16x8 b, f32x4 c) {
    return __builtin_amdgcn_mfma_f32_16x16x32_f16(a, __builtin_bit_cast(f16x8, b), c, 0, 0, 0);
}

// ---------------- prep kernel: blocks 0..255 = s|t GEMM (64x32 tiles, XCD-swizzled);
//                  blocks 256..1155 = weight conversion/permutation ----------------
__global__ __launch_bounds__(256, 3)
void prep_kernel(const float* __restrict__ x, const float* __restrict__ sW,
                 const float* __restrict__ tW, const float* __restrict__ sb,
                 const float* __restrict__ tb, const float* __restrict__ f2W,
                 const float* __restrict__ blW, const float* __restrict__ f3W,
                 u16* __restrict__ STb, u16* __restrict__ blkw, u16* __restrict__ f3wb)
{
    if (blockIdx.x >= 256) {
        int idx = (blockIdx.x - 256) * 256 + threadIdx.x;
        float4 v;
        u16* dst;
        if (idx < 229376) {
            int i4 = idx * 4;
            int r = i4 >> 8, k = i4 & 255;
            const float* src;
            if (r < 3072)      { int n = r >> 8, e = r & 255; src = &blW[(e * 12 + n) * 256 + k]; }
            else if (r < 3328) { src = &f2W[(r - 3072) * 512 + k]; }
            else               { src = &f2W[(r - 3328) * 512 + 256 + k]; }
            v = *(const float4*)src;
            dst = &blkw[i4];
        } else {
            int i4 = (idx - 229376) * 4;
            int row = i4 >> 8, e = i4 & 255;
            if (row < 12) v = *(const float4*)&f3W[row * 256 + e];
            else          v = make_float4(0.f, 0.f, 0.f, 0.f);
            dst = &f3wb[i4];
        }
        ushort4 o;
        o.x = f2h(v.x); o.y = f2h(v.y); o.z = f2h(v.z); o.w = f2h(v.w);
        *(ushort4*)dst = o;
        return;
    }
    // ---- s|t GEMM body: STb = relu(x @ [sW;tW]^T + [sb;tb]), tile 64M x 32N ----
    // XCD remap: block g lands on XCD g&7; XCD k owns m-tiles {2k,2k+1} x all n-tiles
    // -> x stripe (2x196KB) L2-resident per XCD; weight stripes 2x-reused in L2.
    __shared__ u16 As[64 * 72];
    __shared__ u16 Bs[32 * 72];
    const int tid = threadIdx.x;
    const int g = blockIdx.x;
    const int xcd = g & 7, slot = g >> 3;
    const int m0 = (((xcd << 1) | (slot >> 4))) * 64;
    const int n0 = (slot & 15) * 32;
    const int w = tid >> 6, l = tid & 63;
    const int wr = (w >> 1) * 32, wc = (w & 1) * 16;
    const int lr = l & 15, lg = l >> 4;
    const int srow = tid >> 2, kq = tid & 3;

    const float* ap = &x[(size_t)(m0 + srow) * 768 + kq * 16];
    const bool bstg = (tid < 128);
    const float* bp = nullptr;
    if (bstg) {
        int br = n0 + (tid >> 2);
        bp = (br < 256) ? &sW[(size_t)br * 768 + kq * 16]
                        : &tW[(size_t)(br - 256) * 768 + kq * 16];
    }
    float4 ra0 = *(const float4*)(ap + 0),  ra1 = *(const float4*)(ap + 4);
    float4 ra2 = *(const float4*)(ap + 8),  ra3 = *(const float4*)(ap + 12);
    float4 rb0, rb1, rb2, rb3;
    if (bstg) {
        rb0 = *(const float4*)(bp + 0);  rb1 = *(const float4*)(bp + 4);
        rb2 = *(const float4*)(bp + 8);  rb3 = *(const float4*)(bp + 12);
    }

    f32x4 acc[2] = {};
    for (int k0 = 0; k0 < 768; k0 += 64) {
        __syncthreads();
        *(s16x8*)&As[srow * 72 + kq * 16]     = cvt2(ra0, ra1);
        *(s16x8*)&As[srow * 72 + kq * 16 + 8] = cvt2(ra2, ra3);
        if (bstg) {
            *(s16x8*)&Bs[(tid >> 2) * 72 + kq * 16]     = cvt2(rb0, rb1);
            *(s16x8*)&Bs[(tid >> 2) * 72 + kq * 16 + 8] = cvt2(rb2, rb3);
        }
        __syncthreads();
        if (k0 + 64 < 768) {
            ra0 = *(const float4*)(ap + k0 + 64 + 0);  ra1 = *(const float4*)(ap + k0 + 64 + 4);
            ra2 = *(const float4*)(ap + k0 + 64 + 8);  ra3 = *(const float4*)(ap + k0 + 64 + 12);
            if (bstg) {
                rb0 = *(const float4*)(bp + k0 + 64 + 0);  rb1 = *(const float4*)(bp + k0 + 64 + 4);
                rb2 = *(const float4*)(bp + k0 + 64 + 8);  rb3 = *(const float4*)(bp + k0 + 64 + 12);
            }
        }
#pragma unroll
        for (int kk = 0; kk < 64; kk += 32) {
            s16x8 af[2], bf;
            af[0] = *(const s16x8*)&As[(wr      + lr) * 72 + kk + lg * 8];
            af[1] = *(const s16x8*)&As[(wr + 16 + lr) * 72 + kk + lg * 8];
            bf    = *(const s16x8*)&Bs[(wc      + lr) * 72 + kk + lg * 8];
            acc[0] = mfma_f16(af[0], bf, acc[0]);
            acc[1] = mfma_f16(af[1], bf, acc[1]);
        }
    }
#pragma unroll
    for (int fi = 0; fi < 2; ++fi) {
#pragma unroll
        for (int r = 0; r < 4; ++r) {
            int grow = m0 + wr + fi * 16 + lg * 4 + r;
            int gcol = n0 + wc + lr;
            float bias = (gcol < 256) ? sb[gcol] : tb[gcol - 256];
            float v = fmaxf(acc[fi][r] + bias, 0.f);
            STb[(size_t)grow * 512 + gcol] = f2h(v);
        }
    }
}

// ---------------- key+su+tv GEMM: one launch, N=3584, K=256, XCD-swizzled ----------------
// key (cols<3072) written in fragment order:
// KEYF[(((n*64 + i>>4)*8 + e>>5)*64 + ((e>>3)&3)*16 + (i&15))*8 + (e&7)]
__global__ __launch_bounds__(256, 6)
void gemm_kst(const u16* __restrict__ STb, const u16* __restrict__ BLKW,
              const float* __restrict__ f2b,
              u16* __restrict__ KEYF, u16* __restrict__ SUp, u16* __restrict__ TVp)
{
    __shared__ u16 As[64 * 72];
    __shared__ u16 Bs[64 * 72];
    const int tid = threadIdx.x;
    // XCD remap: lin lands on XCD lin&7; XCD k owns n-tiles 7k..7k+6 x all 16 m-tiles
    // -> BLKW col-stripes (7x32KB) L2-resident per XCD (16x reuse each).
    const int lin = blockIdx.x + blockIdx.y * 56;
    const int xcd = lin & 7, slot = lin >> 3;           // slot 0..111
    const int n0 = (xcd * 7 + (slot >> 4)) * 64;
    const int m0 = (slot & 15) * 64;
    const int w = tid >> 6, l = tid & 63;
    const int wr = (w >> 1) * 32, wc = (w & 1) * 32;
    const int lr = l & 15, lg = l >> 4;
    const int srow = tid >> 2, kq = tid & 3;

    const u16* A = STb + (n0 >= 3328 ? 256 : 0);
    const u16* ap = &A[(size_t)(m0 + srow) * 512];
    const u16* bp = &BLKW[(size_t)(n0 + srow) * 256];
    s16x8 ra0 = *(const s16x8*)&ap[kq * 8];
    s16x8 ra1 = *(const s16x8*)&ap[(kq + 4) * 8];
    s16x8 rb0 = *(const s16x8*)&bp[kq * 8];
    s16x8 rb1 = *(const s16x8*)&bp[(kq + 4) * 8];

    f32x4 acc[2][2] = {};
    for (int k0 = 0; k0 < 256; k0 += 64) {
        __syncthreads();
        *(s16x8*)&As[srow * 72 + kq * 8]       = ra0;
        *(s16x8*)&As[srow * 72 + (kq + 4) * 8] = ra1;
        *(s16x8*)&Bs[srow * 72 + kq * 8]       = rb0;
        *(s16x8*)&Bs[srow * 72 + (kq + 4) * 8] = rb1;
        __syncthreads();
        if (k0 + 64 < 256) {
            ra0 = *(const s16x8*)&ap[k0 + 64 + kq * 8];
            ra1 = *(const s16x8*)&ap[k0 + 64 + (kq + 4) * 8];
            rb0 = *(const s16x8*)&bp[k0 + 64 + kq * 8];
            rb1 = *(const s16x8*)&bp[k0 + 64 + (kq + 4) * 8];
        }
#pragma unroll
        for (int kk = 0; kk < 64; kk += 32) {
            s16x8 af[2], bf[2];
            af[0] = *(const s16x8*)&As[(wr      + lr) * 72 + kk + lg * 8];
            af[1] = *(const s16x8*)&As[(wr + 16 + lr) * 72 + kk + lg * 8];
            bf[0] = *(const s16x8*)&Bs[(wc      + lr) * 72 + kk + lg * 8];
            bf[1] = *(const s16x8*)&Bs[(wc + 16 + lr) * 72 + kk + lg * 8];
#pragma unroll
            for (int fi = 0; fi < 2; ++fi)
#pragma unroll
                for (int fj = 0; fj < 2; ++fj)
                    acc[fi][fj] = mfma_f16(af[fi], bf[fj], acc[fi][fj]);
        }
    }
#pragma unroll
    for (int fi = 0; fi < 2; ++fi) {
#pragma unroll
        for (int fj = 0; fj < 2; ++fj) {
#pragma unroll
            for (int r = 0; r < 4; ++r) {
                int grow = m0 + wr + fi * 16 + lg * 4 + r;
                int gcol = n0 + wc + fj * 16 + lr;
                float v = acc[fi][fj][r];
                if (gcol < 3072) {
                    int n = gcol >> 8, e = gcol & 255;
                    int g = grow >> 4, li = grow & 15;
                    int it = e >> 5, sub = (e >> 3) & 3, eo = e & 7;
                    KEYF[((((size_t)n * 64 + g) * 8 + it) * 64 + sub * 16 + li) * 8 + eo] = f2h(v);
                } else if (gcol < 3328) {
                    SUp[(size_t)grow * 256 + (gcol - 3072)] = f2h(v);
                } else {
                    TVp[(size_t)grow * 256 + (gcol - 3328)] = f2h(v + f2b[gcol - 3328]);
                }
            }
        }
    }
}

// ---------------- fused output kernel (unchanged from measured 43.1 version) ----------------
__global__ __launch_bounds__(256, 4)
void fused_out(const u16* __restrict__ KEYF, const u16* __restrict__ STb,
               const u16* __restrict__ SUp, const u16* __restrict__ TVp,
               const u16* __restrict__ F3WH, const float* __restrict__ f3b,
               float* __restrict__ out)
{
    __shared__ __align__(16) char smem[27904];
    u16* lds = (u16*)smem;
    const int TC0 = 0, SUC0 = 2560, TVC0 = 3840, F3C = 6400;

    const int tid = threadIdx.x;
    const int w = tid >> 6, l = tid & 63;

    // XCD-aware bijective remap (nwg=1024, 8 XCDs, 128 per XCD)
    const int lin  = blockIdx.x + (blockIdx.y << 4) + (blockIdx.z << 9);
    const int orig = (lin & 7) * 128 + (lin >> 3);
    const int j0 = (orig & 15) * 32;
    const int i0 = ((orig >> 4) & 31) * 16;
    const int b  = orig >> 9;

    const int lr = l & 15, lg = l >> 4;

    // staging descriptors: t (tid<128), tv (tid>=128); su extra for tid<64
    const u16* src1; int d1;
    if (tid < 128) {
        int jj = tid >> 2, qq = tid & 3;
        src1 = STb + (size_t)(b * 512 + j0 + jj) * 512 + 256 + qq * 8;
        d1 = TC0 + jj * 40 + qq * 8;
    } else {
        int q = tid - 128, jj = q >> 2, qq = q & 3;
        src1 = TVp + (size_t)(b * 512 + j0 + jj) * 256 + qq * 8;
        d1 = TVC0 + jj * 40 + qq * 8;
    }
    const u16* src2 = nullptr; int d2 = 0;
    const bool has2 = (tid < 64);
    if (has2) {
        int ii = tid >> 2, qq = tid & 3;
        src2 = SUp + (size_t)(b * 512 + i0 + ii) * 256 + qq * 8;
        d2 = SUC0 + ii * 40 + qq * 8;
    }

    // f3 staged once
#pragma unroll
    for (int rr = 0; rr < 2; ++rr) {
        int g = tid + 256 * rr;
        int row = g >> 5, qq = g & 31;
        *(s16x8*)&lds[F3C + row * 264 + qq * 8] = *(const s16x8*)&F3WH[row * 256 + qq * 8];
    }

    // key fragment bases (register-direct): wave w owns n = 3w..3w+2
    const int gblk = b * 32 + (i0 >> 4);
    const u16* kfb0 = KEYF + ((size_t)((3 * w + 0) * 64 + gblk) * 8) * 512 + l * 8;
    const u16* kfb1 = KEYF + ((size_t)((3 * w + 1) * 64 + gblk) * 8) * 512 + l * 8;
    const u16* kfb2 = KEYF + ((size_t)((3 * w + 2) * 64 + gblk) * 8) * 512 + l * 8;

    // prologue: stage iter0 into buf0, prefetch kf(it0) and regs for it1
    s16x8 r1 = *(const s16x8*)src1;
    s16x8 r2 = {};
    if (has2) r2 = *(const s16x8*)src2;
    *(s16x8*)&lds[d1] = r1;
    if (has2) *(s16x8*)&lds[d2] = r2;
    s16x8 kf0 = *(const s16x8*)kfb0;
    s16x8 kf1 = *(const s16x8*)kfb1;
    s16x8 kf2 = *(const s16x8*)kfb2;
    r1 = *(const s16x8*)(src1 + 32);
    if (has2) r2 = *(const s16x8*)(src2 + 32);
    __syncthreads();

    f32x4 acc1[3][2] = {};
    f32x4 acc2[8]    = {};

#pragma unroll
    for (int it = 0; it < 8; ++it) {
        const int cur = it & 1, nxt = cur ^ 1;
        // commit next-iter regs into the other buffer (readers use cur)
        if (it < 7) {
            *(s16x8*)&lds[d1 + nxt * 1280] = r1;
            if (has2) *(s16x8*)&lds[d2 + nxt * 640] = r2;
        }
        // ---- out1: 6 mfma (kf in regs, t from LDS) ----
        s16x8 tf0 = *(const s16x8*)&lds[TC0 + cur * 1280 + lr * 40 + lg * 8];
        s16x8 tf1 = *(const s16x8*)&lds[TC0 + cur * 1280 + (16 + lr) * 40 + lg * 8];
        acc1[0][0] = mfma_f16(kf0, tf0, acc1[0][0]);
        acc1[0][1] = mfma_f16(kf0, tf1, acc1[0][1]);
        acc1[1][0] = mfma_f16(kf1, tf0, acc1[1][0]);
        acc1[1][1] = mfma_f16(kf1, tf1, acc1[1][1]);
        acc1[2][0] = mfma_f16(kf2, tf0, acc1[2][0]);
        acc1[2][1] = mfma_f16(kf2, tf1, acc1[2][1]);
        // prefetch next kf (latency hides under out2)
        s16x8 nk0, nk1, nk2;
        if (it < 7) {
            nk0 = *(const s16x8*)(kfb0 + (it + 1) * 512);
            nk1 = *(const s16x8*)(kfb1 + (it + 1) * 512);
            nk2 = *(const s16x8*)(kfb2 + (it + 1) * 512);
        }
        // ---- out2: packed-f16 h + 8 mfma ----
        f16x8 sv = __builtin_bit_cast(f16x8,
            *(const s16x8*)&lds[SUC0 + cur * 640 + lr * 40 + lg * 8]);
        s16x8 f3fr = *(const s16x8*)&lds[F3C + lr * 264 + it * 32 + lg * 8];
#pragma unroll
        for (int jj = 0; jj < 8; ++jj) {
            int j = w * 8 + jj;
            f16x8 tv8 = __builtin_bit_cast(f16x8,
                *(const s16x8*)&lds[TVC0 + cur * 1280 + j * 40 + lg * 8]);
            f16x8 hv = relu8(sv + tv8);
            acc2[jj] = mfma_f16v(hv, f3fr, acc2[jj]);
        }
        // issue global loads for it+2
        if (it < 6) {
            r1 = *(const s16x8*)(src1 + (it + 2) * 32);
            if (has2) r2 = *(const s16x8*)(src2 + (it + 2) * 32);
        }
        if (it < 7) { kf0 = nk0; kf1 = nk1; kf2 = nk2; }
        __syncthreads();   // single barrier per iteration
    }

    // ---- merge out2 D[n=lr][i][j] into out1 layout via LDS (overlay), then store ----
    float* mg = (float*)smem;   // [12] x stride 580 f32; i stride 36
    if (lr < 12) {
#pragma unroll
        for (int r = 0; r < 4; ++r) {
            int i = lg * 4 + r;
            f32x4 v0, v1;
            v0[0] = acc2[0][r]; v0[1] = acc2[1][r]; v0[2] = acc2[2][r]; v0[3] = acc2[3][r];
            v1[0] = acc2[4][r]; v1[1] = acc2[5][r]; v1[2] = acc2[6][r]; v1[3] = acc2[7][r];
            *(f32x4*)&mg[lr * 580 + i * 36 + w * 8]     = v0;
            *(f32x4*)&mg[lr * 580 + i * 36 + w * 8 + 4] = v1;
        }
    }
    __syncthreads();
#pragma unroll
    for (int a = 0; a < 3; ++a) {
        int n = 3 * w + a;
        float fb = f3b[n];
#pragma unroll
        for (int fj = 0; fj < 2; ++fj) {
            int j = fj * 16 + lr;
#pragma unroll
            for (int r = 0; r < 4; ++r) {
                int i = lg * 4 + r;
                float vv = acc1[a][fj][r] + mg[n * 580 + i * 36 + j] + fb;
                out[(((size_t)(b * 512 + i0 + i)) * 12 + n) * 512 + j0 + j] = vv;
            }
        }
    }
}

extern "C" void kernel_launch(void* const* d_in, const int* in_sizes, int n_in,
                              void* d_out, int out_size, void* d_ws, size_t ws_size,
                              hipStream_t stream)
{
    const float* x   = (const float*)d_in[0];
    const float* sW  = (const float*)d_in[1];
    const float* sb  = (const float*)d_in[2];
    const float* tW  = (const float*)d_in[3];
    const float* tb  = (const float*)d_in[4];
    const float* f2W = (const float*)d_in[5];
    const float* f2b = (const float*)d_in[6];
    const float* f3W = (const float*)d_in[7];
    const float* f3b = (const float*)d_in[8];
    const float* blW = (const float*)d_in[9];
    float* out = (float*)d_out;

    char* p = (char*)d_ws;
    u16* STb   = (u16*)p; p += 1048576;   // [1024][512] f16 (s|t)
    u16* blkw  = (u16*)p; p += 1835008;   // [3584][256] f16 (blW perm ; Wu ; Wv)
    u16* KEYF  = (u16*)p; p += 6291456;   // [12][64][8][64][8] f16 fragment order
    u16* SUp   = (u16*)p; p += 524288;    // [1024][256] f16
    u16* TVp   = (u16*)p; p += 524288;    // [1024][256] f16 (tv + f2b)
    u16* f3wbg = (u16*)p; p += 8192;      // [16][256] f16 (f3W zero-padded)

    prep_kernel<<<1156, 256, 0, stream>>>(x, sW, tW, sb, tb, f2W, blW, f3W,
                                          STb, blkw, f3wbg);
    gemm_kst<<<dim3(56, 16), 256, 0, stream>>>(STb, blkw, f2b, KEYF, SUp, TVp);
    fused_out<<<dim3(16, 32, 2), 256, 0, stream>>>(KEYF, STb, SUp, TVp, f3wbg, f3b, out);
}

// Round 12
// 42.658 us; speedup vs baseline: 1.3314x; 1.0012x over previous
//
#include <hip/hip_runtime.h>
#include <hip/hip_bf16.h>

// B=2, L=512, H_IN=768, E=256, N=12. M = B*L = 1024.
// out[b,i,n,j] = sum_e key[b,i,e,n]*t[b,j,e]
//             + sum_e relu(su[b,i,e]+tv[b,j,e]+f2b[e])*f3W[n,e] + f3b[n]
// All intermediates fp16. key stored in MFMA-fragment order (KEYF); fused_out
// reads it register-direct (coalesced 1KB/wave). fused tile 16i x 64j halves
// KEYF L2 re-reads vs 32j.

typedef unsigned short u16;
typedef __attribute__((ext_vector_type(8))) short    s16x8;
typedef __attribute__((ext_vector_type(8))) _Float16 f16x8;
typedef __attribute__((ext_vector_type(4))) float    f32x4;

__device__ inline u16 f2h(float f) { return __builtin_bit_cast(u16, (_Float16)f); }

__device__ inline s16x8 cvt2(float4 a, float4 b) {
    f16x8 h;
    h[0] = (_Float16)a.x; h[1] = (_Float16)a.y; h[2] = (_Float16)a.z; h[3] = (_Float16)a.w;
    h[4] = (_Float16)b.x; h[5] = (_Float16)b.y; h[6] = (_Float16)b.z; h[7] = (_Float16)b.w;
    return __builtin_bit_cast(s16x8, h);
}

__device__ inline f16x8 relu8(f16x8 v) {
#if __has_builtin(__builtin_elementwise_max)
    f16x8 z = {};
    return __builtin_elementwise_max(v, z);
#else
#pragma unroll
    for (int q = 0; q < 8; ++q) v[q] = v[q] > (_Float16)0.f ? v[q] : (_Float16)0.f;
    return v;
#endif
}

__device__ inline f32x4 mfma_f16(s16x8 a, s16x8 b, f32x4 c) {
    return __builtin_amdgcn_mfma_f32_16x16x32_f16(
        __builtin_bit_cast(f16x8, a), __builtin_bit_cast(f16x8, b), c, 0, 0, 0);
}
__device__ inline f32x4 mfma_f16v(f16x8 a, s16x8 b, f32x4 c) {
    return __builtin_amdgcn_mfma_f32_16x16x32_f16(a, __builtin_bit_cast(f16x8, b), c, 0, 0, 0);
}

// ---------------- prep kernel (unchanged): blocks 0..255 = s|t GEMM (64x32, XCD-swz);
//                  blocks 256..1155 = weight conversion/permutation ----------------
__global__ __launch_bounds__(256, 3)
void prep_kernel(const float* __restrict__ x, const float* __restrict__ sW,
                 const float* __restrict__ tW, const float* __restrict__ sb,
                 const float* __restrict__ tb, const float* __restrict__ f2W,
                 const float* __restrict__ blW, const float* __restrict__ f3W,
                 u16* __restrict__ STb, u16* __restrict__ blkw, u16* __restrict__ f3wb)
{
    if (blockIdx.x >= 256) {
        int idx = (blockIdx.x - 256) * 256 + threadIdx.x;
        float4 v;
        u16* dst;
        if (idx < 229376) {
            int i4 = idx * 4;
            int r = i4 >> 8, k = i4 & 255;
            const float* src;
            if (r < 3072)      { int n = r >> 8, e = r & 255; src = &blW[(e * 12 + n) * 256 + k]; }
            else if (r < 3328) { src = &f2W[(r - 3072) * 512 + k]; }
            else               { src = &f2W[(r - 3328) * 512 + 256 + k]; }
            v = *(const float4*)src;
            dst = &blkw[i4];
        } else {
            int i4 = (idx - 229376) * 4;
            int row = i4 >> 8, e = i4 & 255;
            if (row < 12) v = *(const float4*)&f3W[row * 256 + e];
            else          v = make_float4(0.f, 0.f, 0.f, 0.f);
            dst = &f3wb[i4];
        }
        ushort4 o;
        o.x = f2h(v.x); o.y = f2h(v.y); o.z = f2h(v.z); o.w = f2h(v.w);
        *(ushort4*)dst = o;
        return;
    }
    __shared__ u16 As[64 * 72];
    __shared__ u16 Bs[32 * 72];
    const int tid = threadIdx.x;
    const int g = blockIdx.x;
    const int xcd = g & 7, slot = g >> 3;
    const int m0 = (((xcd << 1) | (slot >> 4))) * 64;
    const int n0 = (slot & 15) * 32;
    const int w = tid >> 6, l = tid & 63;
    const int wr = (w >> 1) * 32, wc = (w & 1) * 16;
    const int lr = l & 15, lg = l >> 4;
    const int srow = tid >> 2, kq = tid & 3;

    const float* ap = &x[(size_t)(m0 + srow) * 768 + kq * 16];
    const bool bstg = (tid < 128);
    const float* bp = nullptr;
    if (bstg) {
        int br = n0 + (tid >> 2);
        bp = (br < 256) ? &sW[(size_t)br * 768 + kq * 16]
                        : &tW[(size_t)(br - 256) * 768 + kq * 16];
    }
    float4 ra0 = *(const float4*)(ap + 0),  ra1 = *(const float4*)(ap + 4);
    float4 ra2 = *(const float4*)(ap + 8),  ra3 = *(const float4*)(ap + 12);
    float4 rb0, rb1, rb2, rb3;
    if (bstg) {
        rb0 = *(const float4*)(bp + 0);  rb1 = *(const float4*)(bp + 4);
        rb2 = *(const float4*)(bp + 8);  rb3 = *(const float4*)(bp + 12);
    }

    f32x4 acc[2] = {};
    for (int k0 = 0; k0 < 768; k0 += 64) {
        __syncthreads();
        *(s16x8*)&As[srow * 72 + kq * 16]     = cvt2(ra0, ra1);
        *(s16x8*)&As[srow * 72 + kq * 16 + 8] = cvt2(ra2, ra3);
        if (bstg) {
            *(s16x8*)&Bs[(tid >> 2) * 72 + kq * 16]     = cvt2(rb0, rb1);
            *(s16x8*)&Bs[(tid >> 2) * 72 + kq * 16 + 8] = cvt2(rb2, rb3);
        }
        __syncthreads();
        if (k0 + 64 < 768) {
            ra0 = *(const float4*)(ap + k0 + 64 + 0);  ra1 = *(const float4*)(ap + k0 + 64 + 4);
            ra2 = *(const float4*)(ap + k0 + 64 + 8);  ra3 = *(const float4*)(ap + k0 + 64 + 12);
            if (bstg) {
                rb0 = *(const float4*)(bp + k0 + 64 + 0);  rb1 = *(const float4*)(bp + k0 + 64 + 4);
                rb2 = *(const float4*)(bp + k0 + 64 + 8);  rb3 = *(const float4*)(bp + k0 + 64 + 12);
            }
        }
#pragma unroll
        for (int kk = 0; kk < 64; kk += 32) {
            s16x8 af[2], bf;
            af[0] = *(const s16x8*)&As[(wr      + lr) * 72 + kk + lg * 8];
            af[1] = *(const s16x8*)&As[(wr + 16 + lr) * 72 + kk + lg * 8];
            bf    = *(const s16x8*)&Bs[(wc      + lr) * 72 + kk + lg * 8];
            acc[0] = mfma_f16(af[0], bf, acc[0]);
            acc[1] = mfma_f16(af[1], bf, acc[1]);
        }
    }
#pragma unroll
    for (int fi = 0; fi < 2; ++fi) {
#pragma unroll
        for (int r = 0; r < 4; ++r) {
            int grow = m0 + wr + fi * 16 + lg * 4 + r;
            int gcol = n0 + wc + lr;
            float bias = (gcol < 256) ? sb[gcol] : tb[gcol - 256];
            float v = fmaxf(acc[fi][r] + bias, 0.f);
            STb[(size_t)grow * 512 + gcol] = f2h(v);
        }
    }
}

// ---------------- key+su+tv GEMM (unchanged): N=3584, K=256, XCD-swizzled ----------------
__global__ __launch_bounds__(256, 6)
void gemm_kst(const u16* __restrict__ STb, const u16* __restrict__ BLKW,
              const float* __restrict__ f2b,
              u16* __restrict__ KEYF, u16* __restrict__ SUp, u16* __restrict__ TVp)
{
    __shared__ u16 As[64 * 72];
    __shared__ u16 Bs[64 * 72];
    const int tid = threadIdx.x;
    const int lin = blockIdx.x + blockIdx.y * 56;
    const int xcd = lin & 7, slot = lin >> 3;
    const int n0 = (xcd * 7 + (slot >> 4)) * 64;
    const int m0 = (slot & 15) * 64;
    const int w = tid >> 6, l = tid & 63;
    const int wr = (w >> 1) * 32, wc = (w & 1) * 32;
    const int lr = l & 15, lg = l >> 4;
    const int srow = tid >> 2, kq = tid & 3;

    const u16* A = STb + (n0 >= 3328 ? 256 : 0);
    const u16* ap = &A[(size_t)(m0 + srow) * 512];
    const u16* bp = &BLKW[(size_t)(n0 + srow) * 256];
    s16x8 ra0 = *(const s16x8*)&ap[kq * 8];
    s16x8 ra1 = *(const s16x8*)&ap[(kq + 4) * 8];
    s16x8 rb0 = *(const s16x8*)&bp[kq * 8];
    s16x8 rb1 = *(const s16x8*)&bp[(kq + 4) * 8];

    f32x4 acc[2][2] = {};
    for (int k0 = 0; k0 < 256; k0 += 64) {
        __syncthreads();
        *(s16x8*)&As[srow * 72 + kq * 8]       = ra0;
        *(s16x8*)&As[srow * 72 + (kq + 4) * 8] = ra1;
        *(s16x8*)&Bs[srow * 72 + kq * 8]       = rb0;
        *(s16x8*)&Bs[srow * 72 + (kq + 4) * 8] = rb1;
        __syncthreads();
        if (k0 + 64 < 256) {
            ra0 = *(const s16x8*)&ap[k0 + 64 + kq * 8];
            ra1 = *(const s16x8*)&ap[k0 + 64 + (kq + 4) * 8];
            rb0 = *(const s16x8*)&bp[k0 + 64 + kq * 8];
            rb1 = *(const s16x8*)&bp[k0 + 64 + (kq + 4) * 8];
        }
#pragma unroll
        for (int kk = 0; kk < 64; kk += 32) {
            s16x8 af[2], bf[2];
            af[0] = *(const s16x8*)&As[(wr      + lr) * 72 + kk + lg * 8];
            af[1] = *(const s16x8*)&As[(wr + 16 + lr) * 72 + kk + lg * 8];
            bf[0] = *(const s16x8*)&Bs[(wc      + lr) * 72 + kk + lg * 8];
            bf[1] = *(const s16x8*)&Bs[(wc + 16 + lr) * 72 + kk + lg * 8];
#pragma unroll
            for (int fi = 0; fi < 2; ++fi)
#pragma unroll
                for (int fj = 0; fj < 2; ++fj)
                    acc[fi][fj] = mfma_f16(af[fi], bf[fj], acc[fi][fj]);
        }
    }
#pragma unroll
    for (int fi = 0; fi < 2; ++fi) {
#pragma unroll
        for (int fj = 0; fj < 2; ++fj) {
#pragma unroll
            for (int r = 0; r < 4; ++r) {
                int grow = m0 + wr + fi * 16 + lg * 4 + r;
                int gcol = n0 + wc + fj * 16 + lr;
                float v = acc[fi][fj][r];
                if (gcol < 3072) {
                    int n = gcol >> 8, e = gcol & 255;
                    int g2 = grow >> 4, li = grow & 15;
                    int it = e >> 5, sub = (e >> 3) & 3, eo = e & 7;
                    KEYF[((((size_t)n * 64 + g2) * 8 + it) * 64 + sub * 16 + li) * 8 + eo] = f2h(v);
                } else if (gcol < 3328) {
                    SUp[(size_t)grow * 256 + (gcol - 3072)] = f2h(v);
                } else {
                    TVp[(size_t)grow * 256 + (gcol - 3328)] = f2h(v + f2b[gcol - 3328]);
                }
            }
        }
    }
}

// ---------------- fused output kernel: 16i x 64j tile, 512 thr = 8 waves ----------------
// wave w: out1 -> n-triple wn=w&3, j-half jh=w>>2; out2 -> j in [w*8, w*8+8).
// kf register-direct from KEYF (waves w, w+4 share loads via L1). t/su/tv double-
// buffered LDS, one barrier per iter. Grid 512 (8 jt, 32 it, 2 b), XCD-swizzled.
__global__ __launch_bounds__(512, 4)
void fused_out(const u16* __restrict__ KEYF, const u16* __restrict__ STb,
               const u16* __restrict__ SUp, const u16* __restrict__ TVp,
               const u16* __restrict__ F3WH, const float* __restrict__ f3b,
               float* __restrict__ out)
{
    __shared__ __align__(16) char smem[31488];
    u16* lds = (u16*)smem;
    // u16 offs: TC[2] @0 (64x40, stride 2560) | SUC[2] @5120 (16x40, stride 640)
    //           TVC[2] @6400 (64x40, stride 2560) | F3C @11520 (16x264) -> 15744 u16
    const int TC0 = 0, SUC0 = 5120, TVC0 = 6400, F3C = 11520;

    const int tid = threadIdx.x;
    const int w = tid >> 6, l = tid & 63;

    // XCD-aware bijective remap (nwg=512, 8 XCDs, 64 per XCD -> 8 i0 x 8 jt each)
    const int lin  = blockIdx.x + (blockIdx.y << 3) + (blockIdx.z << 8);
    const int orig = (lin & 7) * 64 + (lin >> 3);
    const int j0 = (orig & 7) * 64;
    const int i0 = ((orig >> 3) & 31) * 16;
    const int b  = orig >> 8;

    const int lr = l & 15, lg = l >> 4;
    const int wn = w & 3, jh = w >> 2;

    // staging: tid<256 -> t tile (64x4 granules); tid>=256 -> tv; tid<64 also su
    const u16* src1; int d1;
    if (tid < 256) {
        int jj = tid >> 2, qq = tid & 3;
        src1 = STb + (size_t)(b * 512 + j0 + jj) * 512 + 256 + qq * 8;
        d1 = TC0 + jj * 40 + qq * 8;
    } else {
        int q = tid - 256, jj = q >> 2, qq = q & 3;
        src1 = TVp + (size_t)(b * 512 + j0 + jj) * 256 + qq * 8;
        d1 = TVC0 + jj * 40 + qq * 8;
    }
    const bool has2 = (tid < 64);
    const u16* src2 = nullptr; int d2 = 0;
    if (has2) {
        int ii = tid >> 2, qq = tid & 3;
        src2 = SUp + (size_t)(b * 512 + i0 + ii) * 256 + qq * 8;
        d2 = SUC0 + ii * 40 + qq * 8;
    }

    { // f3 staged once: 512 granules, 1 per thread
        int row = tid >> 5, qq = tid & 31;
        *(s16x8*)&lds[F3C + row * 264 + qq * 8] = *(const s16x8*)&F3WH[row * 256 + qq * 8];
    }

    // key fragment bases: wave w owns n = 3*wn..3*wn+2 (waves w and w+4 identical)
    const int gblk = b * 32 + (i0 >> 4);
    const u16* kfb0 = KEYF + ((size_t)((3 * wn + 0) * 64 + gblk) * 8) * 512 + l * 8;
    const u16* kfb1 = KEYF + ((size_t)((3 * wn + 1) * 64 + gblk) * 8) * 512 + l * 8;
    const u16* kfb2 = KEYF + ((size_t)((3 * wn + 2) * 64 + gblk) * 8) * 512 + l * 8;

    // prologue
    s16x8 r1 = *(const s16x8*)src1;
    s16x8 r2 = {};
    if (has2) r2 = *(const s16x8*)src2;
    *(s16x8*)&lds[d1] = r1;
    if (has2) *(s16x8*)&lds[d2] = r2;
    s16x8 kf0 = *(const s16x8*)kfb0;
    s16x8 kf1 = *(const s16x8*)kfb1;
    s16x8 kf2 = *(const s16x8*)kfb2;
    r1 = *(const s16x8*)(src1 + 32);
    if (has2) r2 = *(const s16x8*)(src2 + 32);
    __syncthreads();

    f32x4 acc1[3][2] = {};
    f32x4 acc2[8]    = {};

#pragma unroll
    for (int it = 0; it < 8; ++it) {
        const int cur = it & 1, nxt = cur ^ 1;
        if (it < 7) {
            *(s16x8*)&lds[d1 + nxt * 2560] = r1;
            if (has2) *(s16x8*)&lds[d2 + nxt * 640] = r2;
        }
        // ---- out1: 6 mfma (kf in regs, t half-tile from LDS) ----
        s16x8 tf0 = *(const s16x8*)&lds[TC0 + cur * 2560 + (jh * 32      + lr) * 40 + lg * 8];
        s16x8 tf1 = *(const s16x8*)&lds[TC0 + cur * 2560 + (jh * 32 + 16 + lr) * 40 + lg * 8];
        acc1[0][0] = mfma_f16(kf0, tf0, acc1[0][0]);
        acc1[0][1] = mfma_f16(kf0, tf1, acc1[0][1]);
        acc1[1][0] = mfma_f16(kf1, tf0, acc1[1][0]);
        acc1[1][1] = mfma_f16(kf1, tf1, acc1[1][1]);
        acc1[2][0] = mfma_f16(kf2, tf0, acc1[2][0]);
        acc1[2][1] = mfma_f16(kf2, tf1, acc1[2][1]);
        // prefetch next kf in place (out1 done with current values)
        if (it < 7) {
            kf0 = *(const s16x8*)(kfb0 + (it + 1) * 512);
            kf1 = *(const s16x8*)(kfb1 + (it + 1) * 512);
            kf2 = *(const s16x8*)(kfb2 + (it + 1) * 512);
        }
        // ---- out2: packed-f16 h + 8 mfma (wave's private 8 j columns) ----
        f16x8 sv = __builtin_bit_cast(f16x8,
            *(const s16x8*)&lds[SUC0 + cur * 640 + lr * 40 + lg * 8]);
        s16x8 f3fr = *(const s16x8*)&lds[F3C + lr * 264 + it * 32 + lg * 8];
#pragma unroll
        for (int jj = 0; jj < 8; ++jj) {
            int j = w * 8 + jj;
            f16x8 tv8 = __builtin_bit_cast(f16x8,
                *(const s16x8*)&lds[TVC0 + cur * 2560 + j * 40 + lg * 8]);
            f16x8 hv = relu8(sv + tv8);
            acc2[jj] = mfma_f16v(hv, f3fr, acc2[jj]);
        }
        // issue staged loads for it+2
        if (it < 6) {
            r1 = *(const s16x8*)(src1 + (it + 2) * 32);
            if (has2) r2 = *(const s16x8*)(src2 + (it + 2) * 32);
        }
        __syncthreads();
    }

    // ---- merge out2 D[n=lr][i][j] into out1 layout via LDS (2 chunks of 6 n) ----
    float* mg = (float*)smem;   // chunk: [6] x stride 1092 f32, i stride 68 (bank-offset 4)
#pragma unroll
    for (int nc = 0; nc < 2; ++nc) {
        __syncthreads();
        const int nb = nc * 6;
        const int lrp = lr - nb;
        if (lrp >= 0 && lrp < 6) {
#pragma unroll
            for (int r = 0; r < 4; ++r) {
                int i = lg * 4 + r;
                f32x4 v0, v1;
                v0[0] = acc2[0][r]; v0[1] = acc2[1][r]; v0[2] = acc2[2][r]; v0[3] = acc2[3][r];
                v1[0] = acc2[4][r]; v1[1] = acc2[5][r]; v1[2] = acc2[6][r]; v1[3] = acc2[7][r];
                *(f32x4*)&mg[lrp * 1092 + i * 68 + w * 8]     = v0;
                *(f32x4*)&mg[lrp * 1092 + i * 68 + w * 8 + 4] = v1;
            }
        }
        __syncthreads();
        if ((wn >> 1) == nc) {
#pragma unroll
            for (int a = 0; a < 3; ++a) {
                int n = 3 * wn + a;
                float fb = f3b[n];
#pragma unroll
                for (int fj = 0; fj < 2; ++fj) {
                    int j = jh * 32 + fj * 16 + lr;
#pragma unroll
                    for (int r = 0; r < 4; ++r) {
                        int i = lg * 4 + r;
                        float vv = acc1[a][fj][r] + mg[(n - nb) * 1092 + i * 68 + j] + fb;
                        out[(((size_t)(b * 512 + i0 + i)) * 12 + n) * 512 + j0 + j] = vv;
                    }
                }
            }
        }
    }
}

extern "C" void kernel_launch(void* const* d_in, const int* in_sizes, int n_in,
                              void* d_out, int out_size, void* d_ws, size_t ws_size,
                              hipStream_t stream)
{
    const float* x   = (const float*)d_in[0];
    const float* sW  = (const float*)d_in[1];
    const float* sb  = (const float*)d_in[2];
    const float* tW  = (const float*)d_in[3];
    const float* tb  = (const float*)d_in[4];
    const float* f2W = (const float*)d_in[5];
    const float* f2b = (const float*)d_in[6];
    const float* f3W = (const float*)d_in[7];
    const float* f3b = (const float*)d_in[8];
    const float* blW = (const float*)d_in[9];
    float* out = (float*)d_out;

    char* p = (char*)d_ws;
    u16* STb   = (u16*)p; p += 1048576;   // [1024][512] f16 (s|t)
    u16* blkw  = (u16*)p; p += 1835008;   // [3584][256] f16 (blW perm ; Wu ; Wv)
    u16* KEYF  = (u16*)p; p += 6291456;   // [12][64][8][64][8] f16 fragment order
    u16* SUp   = (u16*)p; p += 524288;    // [1024][256] f16
    u16* TVp   = (u16*)p; p += 524288;    // [1024][256] f16 (tv + f2b)
    u16* f3wbg = (u16*)p; p += 8192;      // [16][256] f16 (f3W zero-padded)

    prep_kernel<<<1156, 256, 0, stream>>>(x, sW, tW, sb, tb, f2W, blW, f3W,
                                          STb, blkw, f3wbg);
    gemm_kst<<<dim3(56, 16), 256, 0, stream>>>(STb, blkw, f2b, KEYF, SUp, TVp);
    fused_out<<<dim3(8, 32, 2), 512, 0, stream>>>(KEYF, STb, SUp, TVp, f3wbg, f3b, out);
}